// Round 1
// baseline (1166.602 us; speedup 1.0000x reference)
//
#include <hip/hip_runtime.h>

#define NG 500
#define NPG 100
#define EPG 800
#define INDIM 64
#define HID 128
#define ETOT (NG*EPG)
#define NTOT (NG*NPG)
#define KKEEP 640
#define KDROP 160
#define MAXDEG 64

// output section offsets (in floats)
#define OFF_CX    0u
#define OFF_CEI   6400000u
#define OFF_CATTR 7040000u
#define OFF_CW    7360000u
#define OFF_CB    7680000u
#define OFF_FX    7730000u
#define OFF_FEI   14130000u
#define OFF_FATTR 14290000u
#define OFF_FW    14370000u
#define OFF_FB    14450000u
#define OFF_ES    14500000u

// ---------------------------------------------------------------------------
// LEConv: out = segsum((a[src]-b[dst])*ew, dst) + x@w3 + b3,
//         a = x@w1+b1, b = x@w2
// Factored: agg[d] = sum_e ew*a[src_e]  -  b[d]*sdeg[d]
// One block per graph. Deterministic (fixed per-node edge lists, no atomics).
// ---------------------------------------------------------------------------
template<int K, bool RELU>
__global__ __launch_bounds__(256, 1) void leconv_kernel(
    const float* __restrict__ xin, const int* __restrict__ ei, const float* __restrict__ ea,
    const float* __restrict__ w1, const float* __restrict__ b1,
    const float* __restrict__ w2, const float* __restrict__ w3, const float* __restrict__ b3,
    float* __restrict__ hout)
{
  __shared__ __align__(16) float xt[NPG][K];
  __shared__ __align__(16) float am[NPG][HID];
  __shared__ unsigned char esrc[EPG];
  __shared__ unsigned char edst[EPG];
  __shared__ float ewv[EPG];
  __shared__ float sdeg[NPG];
  __shared__ int   ecnt[NPG];
  __shared__ unsigned short elist[NPG][MAXDEG];

  const int g = blockIdx.x, t = threadIdx.x;
  const int nb = g * NPG;

  for (int i = t; i < NPG * K; i += 256) {
    int n = i / K, k = i - n * K;
    xt[n][k] = xin[(size_t)(nb + n) * K + k];
  }
  for (int e = t; e < EPG; e += 256) {
    int ge = g * EPG + e;
    esrc[e] = (unsigned char)(ei[ge] - nb);
    edst[e] = (unsigned char)(ei[ETOT + ge] - nb);
    ewv[e] = ea[ge];
  }
  __syncthreads();

  const int c = t & 63, grp = t >> 6;
  const int n0 = grp * 25;

  // a = x@w1 + b1, columns c and c+64
  {
    float acc0[25], acc1[25];
    const float bb0 = b1[c], bb1 = b1[c + 64];
#pragma unroll
    for (int i = 0; i < 25; i++) { acc0[i] = bb0; acc1[i] = bb1; }
    for (int k = 0; k < K; k += 4) {
      const float* wp = &w1[(size_t)k * HID + c];
      const float wa0 = wp[0], wa1 = wp[HID], wa2 = wp[2 * HID], wa3 = wp[3 * HID];
      const float wb0 = wp[64], wb1 = wp[HID + 64], wb2 = wp[2 * HID + 64], wb3 = wp[3 * HID + 64];
#pragma unroll
      for (int i = 0; i < 25; i++) {
        const float4 xv = *(const float4*)&xt[n0 + i][k];
        acc0[i] += xv.x * wa0; acc0[i] += xv.y * wa1; acc0[i] += xv.z * wa2; acc0[i] += xv.w * wa3;
        acc1[i] += xv.x * wb0; acc1[i] += xv.y * wb1; acc1[i] += xv.z * wb2; acc1[i] += xv.w * wb3;
      }
    }
#pragma unroll
    for (int i = 0; i < 25; i++) { am[n0 + i][c] = acc0[i]; am[n0 + i][c + 64] = acc1[i]; }
  }

  // per-node incoming edge lists + weighted degree (deterministic order)
  if (t < NPG) {
    int cnt = 0; float s = 0.f;
    for (int e = 0; e < EPG; e++) {
      if ((int)edst[e] == t) {
        if (cnt < MAXDEG) elist[t][cnt] = (unsigned short)e;
        cnt++; s += ewv[e];
      }
    }
    ecnt[t] = cnt < MAXDEG ? cnt : MAXDEG;
    sdeg[t] = s;
  }
  __syncthreads();

  // b = x@w2, cdot = x@w3; out = agg - b*sdeg + cdot + b3
  {
    float accB0[25], accB1[25], accC0[25], accC1[25];
#pragma unroll
    for (int i = 0; i < 25; i++) { accB0[i] = 0.f; accB1[i] = 0.f; accC0[i] = 0.f; accC1[i] = 0.f; }
    for (int k = 0; k < K; k += 4) {
      const float* p2 = &w2[(size_t)k * HID + c];
      const float u0 = p2[0], u1 = p2[HID], u2 = p2[2 * HID], u3 = p2[3 * HID];
      const float v0 = p2[64], v1 = p2[HID + 64], v2 = p2[2 * HID + 64], v3 = p2[3 * HID + 64];
      const float* p3 = &w3[(size_t)k * HID + c];
      const float r0 = p3[0], r1 = p3[HID], r2 = p3[2 * HID], r3 = p3[3 * HID];
      const float s0 = p3[64], s1 = p3[HID + 64], s2 = p3[2 * HID + 64], s3 = p3[3 * HID + 64];
#pragma unroll
      for (int i = 0; i < 25; i++) {
        const float4 xv = *(const float4*)&xt[n0 + i][k];
        accB0[i] += xv.x * u0; accB0[i] += xv.y * u1; accB0[i] += xv.z * u2; accB0[i] += xv.w * u3;
        accB1[i] += xv.x * v0; accB1[i] += xv.y * v1; accB1[i] += xv.z * v2; accB1[i] += xv.w * v3;
        accC0[i] += xv.x * r0; accC0[i] += xv.y * r1; accC0[i] += xv.z * r2; accC0[i] += xv.w * r3;
        accC1[i] += xv.x * s0; accC1[i] += xv.y * s1; accC1[i] += xv.z * s2; accC1[i] += xv.w * s3;
      }
    }
    const float b30 = b3[c], b31 = b3[c + 64];
#pragma unroll
    for (int i = 0; i < 25; i++) {
      const int d = n0 + i;
      const int cn = ecnt[d]; const float sd = sdeg[d];
      float A0 = 0.f, A1 = 0.f;
      for (int j = 0; j < cn; j++) {
        const int e = elist[d][j];
        const int sl = esrc[e];
        const float w = ewv[e];
        A0 += w * am[sl][c];
        A1 += w * am[sl][c + 64];
      }
      float o0 = A0 - accB0[i] * sd + accC0[i] + b30;
      float o1 = A1 - accB1[i] * sd + accC1[i] + b31;
      if (RELU) { o0 = fmaxf(o0, 0.f); o1 = fmaxf(o1, 0.f); }
      hout[(size_t)(nb + d) * HID + c] = o0;
      hout[(size_t)(nb + d) * HID + c + 64] = o1;
    }
  }
}

// ---------------------------------------------------------------------------
// Fused per-graph edge scorer: P = h@W1[0:128]+b1, Q = h@W1[128:256] computed
// in LDS chunks of 64 cols; per-edge score = sum relu(P[s]+Q[d])*w2 in FP64.
// ---------------------------------------------------------------------------
__global__ __launch_bounds__(256, 1) void score_kernel(
    const float* __restrict__ h2, const int* __restrict__ ei,
    const float* __restrict__ w1, const float* __restrict__ b1,
    const float* __restrict__ w2, const float* __restrict__ b2,
    float* __restrict__ scores_ws, float* __restrict__ out_es)
{
  __shared__ __align__(16) float ht[NPG][HID];
  __shared__ float Pm[NPG][65];
  __shared__ float Qm[NPG][65];
  __shared__ unsigned char esrc[EPG];
  __shared__ unsigned char edst[EPG];
  __shared__ float w2l[4 * HID];

  const int g = blockIdx.x, t = threadIdx.x;
  const int nb = g * NPG;

  for (int i = t; i < NPG * HID; i += 256) { int n = i >> 7, k = i & 127; ht[n][k] = h2[(size_t)(nb + n) * HID + k]; }
  for (int e = t; e < EPG; e += 256) {
    int ge = g * EPG + e;
    esrc[e] = (unsigned char)(ei[ge] - nb);
    edst[e] = (unsigned char)(ei[ETOT + ge] - nb);
  }
  for (int i = t; i < 512; i += 256) w2l[i] = w2[i];
  __syncthreads();

  const int c = t & 63, grp = t >> 6, n0 = grp * 25;
  const int e0 = t, e1 = t + 256, e2 = t + 512, e3 = t + 768;
  const int s0l = esrc[e0], d0l = edst[e0];
  const int s1l = esrc[e1], d1l = edst[e1];
  const int s2l = esrc[e2], d2l = edst[e2];
  int s3l = 0, d3l = 0;
  if (t < 32) { s3l = esrc[e3]; d3l = edst[e3]; }
  double a0 = 0., a1 = 0., a2 = 0., a3 = 0.;

  for (int ch = 0; ch < 8; ++ch) {
    const int j0 = ch * 64;
    float accP[25], accQ[25];
    const float bp = b1[j0 + c];
#pragma unroll
    for (int i = 0; i < 25; i++) { accP[i] = bp; accQ[i] = 0.f; }
    for (int k = 0; k < HID; k += 4) {
      const float* wp = &w1[(size_t)k * 512 + j0 + c];
      const float p0 = wp[0], p1 = wp[512], p2v = wp[1024], p3v = wp[1536];
      const float* wq = &w1[(size_t)(HID + k) * 512 + j0 + c];
      const float q0 = wq[0], q1 = wq[512], q2v = wq[1024], q3v = wq[1536];
#pragma unroll
      for (int i = 0; i < 25; i++) {
        const float4 hv = *(const float4*)&ht[n0 + i][k];
        accP[i] += hv.x * p0; accP[i] += hv.y * p1; accP[i] += hv.z * p2v; accP[i] += hv.w * p3v;
        accQ[i] += hv.x * q0; accQ[i] += hv.y * q1; accQ[i] += hv.z * q2v; accQ[i] += hv.w * q3v;
      }
    }
    __syncthreads();   // previous chunk's edge phase done reading Pm/Qm
#pragma unroll
    for (int i = 0; i < 25; i++) { Pm[n0 + i][c] = accP[i]; Qm[n0 + i][c] = accQ[i]; }
    __syncthreads();

    {
      double aa = 0.;
      for (int j = 0; j < 64; j++) {
        const float p = Pm[s0l][j] + Qm[d0l][j];
        aa += (double)fmaxf(p, 0.f) * (double)w2l[j0 + j];
      }
      a0 += aa;
    }
    {
      double aa = 0.;
      for (int j = 0; j < 64; j++) {
        const float p = Pm[s1l][j] + Qm[d1l][j];
        aa += (double)fmaxf(p, 0.f) * (double)w2l[j0 + j];
      }
      a1 += aa;
    }
    {
      double aa = 0.;
      for (int j = 0; j < 64; j++) {
        const float p = Pm[s2l][j] + Qm[d2l][j];
        aa += (double)fmaxf(p, 0.f) * (double)w2l[j0 + j];
      }
      a2 += aa;
    }
    if (t < 32) {
      double aa = 0.;
      for (int j = 0; j < 64; j++) {
        const float p = Pm[s3l][j] + Qm[d3l][j];
        aa += (double)fmaxf(p, 0.f) * (double)w2l[j0 + j];
      }
      a3 += aa;
    }
  }

  const double b2v = (double)b2[0];
  { const float sc = (float)(a0 + b2v); const int ge = g * EPG + e0; scores_ws[ge] = sc; out_es[ge] = sc; }
  { const float sc = (float)(a1 + b2v); const int ge = g * EPG + e1; scores_ws[ge] = sc; out_es[ge] = sc; }
  { const float sc = (float)(a2 + b2v); const int ge = g * EPG + e2; scores_ws[ge] = sc; out_es[ge] = sc; }
  if (t < 32) { const float sc = (float)(a3 + b2v); const int ge = g * EPG + e3; scores_ws[ge] = sc; out_es[ge] = sc; }
}

// ---------------------------------------------------------------------------
// Per-graph stable descending sort of 800 scores (bitonic on packed u64 keys),
// top-K split, presence marking, local relabel ranks.
// ---------------------------------------------------------------------------
__global__ __launch_bounds__(256, 1) void sort_kernel(
    const float* __restrict__ scores, const int* __restrict__ ei,
    int* __restrict__ keptEid, int* __restrict__ dropEid,
    int* __restrict__ cLocal, int* __restrict__ fLocal,
    int* __restrict__ cCount, int* __restrict__ fCount)
{
  __shared__ unsigned long long keys[1024];
  __shared__ int cpres[NPG];
  __shared__ int fpres[NPG];
  const int g = blockIdx.x, t = threadIdx.x;
  const int nb = g * NPG;

  for (int i = t; i < 1024; i += 256) {
    unsigned long long kk;
    if (i < EPG) {
      const float sc = scores[g * EPG + i];
      const unsigned int b = __float_as_uint(sc);
      const unsigned int m = (b & 0x80000000u) ? (~b) : (b | 0x80000000u); // ascending map
      const unsigned int k1 = ~m;                                          // descending score
      kk = ((unsigned long long)k1 << 32) | (unsigned int)i;               // idx asc tiebreak
    } else {
      kk = 0xFFFFFFFFFFFFFFFFull;
    }
    keys[i] = kk;
  }
  for (int i = t; i < NPG; i += 256) { cpres[i] = 0; fpres[i] = 0; }
  __syncthreads();

  for (int k = 2; k <= 1024; k <<= 1) {
    for (int j = k >> 1; j > 0; j >>= 1) {
      for (int i = t; i < 1024; i += 256) {
        const int l = i ^ j;
        if (l > i) {
          const bool up = ((i & k) == 0);
          const unsigned long long va = keys[i], vb = keys[l];
          if ((va > vb) == up) { keys[i] = vb; keys[l] = va; }
        }
      }
      __syncthreads();
    }
  }

  for (int r = t; r < EPG; r += 256) {
    const int el = (int)(unsigned int)keys[r];
    const int ge = g * EPG + el;
    const int sl = ei[ge] - nb, dl = ei[ETOT + ge] - nb;
    if (r < KKEEP) {
      keptEid[g * KKEEP + r] = ge;
      cpres[sl] = 1; cpres[dl] = 1;
    } else {
      dropEid[g * KDROP + (r - KKEEP)] = ge;
      fpres[sl] = 1; fpres[dl] = 1;
    }
  }
  __syncthreads();

  if (t == 0) {
    int cc = 0;
    for (int v = 0; v < NPG; v++) { const int p = cpres[v]; cLocal[nb + v] = p ? cc : -1; cc += p; }
    cCount[g] = cc;
  }
  if (t == 64) {
    int fc = 0;
    for (int v = 0; v < NPG; v++) { const int p = fpres[v]; fLocal[nb + v] = p ? fc : -1; fc += p; }
    fCount[g] = fc;
  }
}

// exclusive scan of 500 per-graph unique counts (both sides) in one block
__global__ __launch_bounds__(512) void offsets_kernel(
    const int* __restrict__ cCount, const int* __restrict__ fCount,
    int* __restrict__ cOff, int* __restrict__ fOff)
{
  __shared__ int sc[512];
  __shared__ int sf[512];
  const int t = threadIdx.x;
  const int c0 = (t < NG) ? cCount[t] : 0;
  const int f0 = (t < NG) ? fCount[t] : 0;
  sc[t] = c0; sf[t] = f0;
  __syncthreads();
  for (int off = 1; off < 512; off <<= 1) {
    const int ac = (t >= off) ? sc[t - off] : 0;
    const int af = (t >= off) ? sf[t - off] : 0;
    __syncthreads();
    sc[t] += ac; sf[t] += af;
    __syncthreads();
  }
  if (t < NG) { cOff[t] = sc[t] - c0; fOff[t] = sf[t] - f0; }
  if (t == NG - 1) { cOff[NG] = sc[t]; fOff[NG] = sf[t]; }
}

// scatter h rows of present nodes into compacted c_x / f_x, write node_idx & batch
__global__ __launch_bounds__(256) void scatter_kernel(
    const float* __restrict__ h2, const int* __restrict__ cLocal, const int* __restrict__ fLocal,
    const int* __restrict__ cOff, const int* __restrict__ fOff,
    int* __restrict__ nodeIdxC, int* __restrict__ nodeIdxF, float* __restrict__ out)
{
  const int tid = blockIdx.x * 256 + threadIdx.x;
  if (tid >= 2 * NTOT * 32) return;
  const int side = tid >= NTOT * 32 ? 1 : 0;
  const int rem = tid - side * NTOT * 32;
  const int v = rem >> 5, q = rem & 31;
  const int loc = side ? fLocal[v] : cLocal[v];
  if (loc < 0) return;
  const int g = v / NPG;
  const int pos = (side ? fOff[g] : cOff[g]) + loc;
  const float4* srcv = (const float4*)(h2 + (size_t)v * HID);
  float4* dstv = (float4*)(out + (side ? OFF_FX : OFF_CX) + (size_t)pos * HID);
  dstv[q] = srcv[q];
  if (q == 0) {
    (side ? nodeIdxF : nodeIdxC)[v] = pos;
    out[(side ? OFF_FB : OFF_CB) + pos] = (float)g;
  }
}

// zero-fill pad rows (unique count < N) and batch = -1
__global__ __launch_bounds__(256) void fill_kernel(
    const int* __restrict__ cOff, const int* __restrict__ fOff, float* __restrict__ out)
{
  const int tid = blockIdx.x * 256 + threadIdx.x;
  if (tid >= 2 * NTOT * 32) return;
  const int side = tid >= NTOT * 32 ? 1 : 0;
  const int rem = tid - side * NTOT * 32;
  const int r = rem >> 5, q = rem & 31;
  const int total = side ? fOff[NG] : cOff[NG];
  if (r < total) return;
  float4 z; z.x = 0.f; z.y = 0.f; z.z = 0.f; z.w = 0.f;
  ((float4*)(out + (side ? OFF_FX : OFF_CX)))[(size_t)r * 32 + q] = z;
  if (q == 0) out[(side ? OFF_FB : OFF_CB) + r] = -1.0f;
}

// remapped edge indices + gathered attr/weight outputs
__global__ __launch_bounds__(256) void edgeout_kernel(
    const int* __restrict__ ei, const float* __restrict__ ea, const float* __restrict__ scores,
    const int* __restrict__ keptEid, const int* __restrict__ dropEid,
    const int* __restrict__ nodeIdxC, const int* __restrict__ nodeIdxF, float* __restrict__ out)
{
  const int tid = blockIdx.x * 256 + threadIdx.x;
  if (tid >= ETOT) return;
  if (tid < NG * KKEEP) {
    const int ge = keptEid[tid];
    out[OFF_CEI + tid] = (float)nodeIdxC[ei[ge]];
    out[OFF_CEI + 320000 + tid] = (float)nodeIdxC[ei[ETOT + ge]];
    out[OFF_CATTR + tid] = ea[ge];
    out[OFF_CW + tid] = scores[ge];
  } else {
    const int i = tid - NG * KKEEP;
    const int ge = dropEid[i];
    out[OFF_FEI + i] = (float)nodeIdxF[ei[ge]];
    out[OFF_FEI + 80000 + i] = (float)nodeIdxF[ei[ETOT + ge]];
    out[OFF_FATTR + i] = ea[ge];
    out[OFF_FW + i] = -scores[ge];
  }
}

extern "C" void kernel_launch(void* const* d_in, const int* in_sizes, int n_in,
                              void* d_out, int out_size, void* d_ws, size_t ws_size,
                              hipStream_t stream) {
  const float* x    = (const float*)d_in[0];
  const int*   ei   = (const int*)d_in[1];
  const float* ea   = (const float*)d_in[2];
  const float* c1w1 = (const float*)d_in[4];
  const float* c1b1 = (const float*)d_in[5];
  const float* c1w2 = (const float*)d_in[6];
  const float* c1w3 = (const float*)d_in[7];
  const float* c1b3 = (const float*)d_in[8];
  const float* c2w1 = (const float*)d_in[9];
  const float* c2b1 = (const float*)d_in[10];
  const float* c2w2 = (const float*)d_in[11];
  const float* c2w3 = (const float*)d_in[12];
  const float* c2b3 = (const float*)d_in[13];
  const float* mw1  = (const float*)d_in[14];
  const float* mb1  = (const float*)d_in[15];
  const float* mw2  = (const float*)d_in[16];
  const float* mb2  = (const float*)d_in[17];
  float* out = (float*)d_out;

  char* p = (char*)d_ws;
  auto carve = [&](size_t bytes) { void* r = (void*)p; p += (bytes + 255) & ~(size_t)255; return r; };
  float* h1      = (float*)carve((size_t)NTOT * HID * 4);
  float* h2      = (float*)carve((size_t)NTOT * HID * 4);
  float* scores  = (float*)carve((size_t)ETOT * 4);
  int* keptEid   = (int*)carve((size_t)NG * KKEEP * 4);
  int* dropEid   = (int*)carve((size_t)NG * KDROP * 4);
  int* cLocal    = (int*)carve((size_t)NTOT * 4);
  int* fLocal    = (int*)carve((size_t)NTOT * 4);
  int* cCount    = (int*)carve((size_t)NG * 4);
  int* fCount    = (int*)carve((size_t)NG * 4);
  int* cOff      = (int*)carve((size_t)(NG + 1) * 4);
  int* fOff      = (int*)carve((size_t)(NG + 1) * 4);
  int* nodeIdxC  = (int*)carve((size_t)NTOT * 4);
  int* nodeIdxF  = (int*)carve((size_t)NTOT * 4);

  leconv_kernel<INDIM, true><<<NG, 256, 0, stream>>>(x, ei, ea, c1w1, c1b1, c1w2, c1w3, c1b3, h1);
  leconv_kernel<HID, false><<<NG, 256, 0, stream>>>(h1, ei, ea, c2w1, c2b1, c2w2, c2w3, c2b3, h2);
  score_kernel<<<NG, 256, 0, stream>>>(h2, ei, mw1, mb1, mw2, mb2, scores, out + OFF_ES);
  sort_kernel<<<NG, 256, 0, stream>>>(scores, ei, keptEid, dropEid, cLocal, fLocal, cCount, fCount);
  offsets_kernel<<<1, 512, 0, stream>>>(cCount, fCount, cOff, fOff);
  const int sc_threads = 2 * NTOT * 32;
  scatter_kernel<<<(sc_threads + 255) / 256, 256, 0, stream>>>(h2, cLocal, fLocal, cOff, fOff, nodeIdxC, nodeIdxF, out);
  fill_kernel<<<(sc_threads + 255) / 256, 256, 0, stream>>>(cOff, fOff, out);
  edgeout_kernel<<<(ETOT + 255) / 256, 256, 0, stream>>>(ei, ea, scores, keptEid, dropEid, nodeIdxC, nodeIdxF, out);
}

// Round 2
// 1148.794 us; speedup vs baseline: 1.0155x; 1.0155x over previous
//
#include <hip/hip_runtime.h>

#define NG 500
#define NPG 100
#define EPG 800
#define INDIM 64
#define HID 128
#define ETOT (NG*EPG)
#define NTOT (NG*NPG)
#define KKEEP 640
#define KDROP 160
#define MAXDEG 64

// output section offsets (in floats)
#define OFF_CX    0u
#define OFF_CEI   6400000u
#define OFF_CATTR 7040000u
#define OFF_CW    7360000u
#define OFF_CB    7680000u
#define OFF_FX    7730000u
#define OFF_FEI   14130000u
#define OFF_FATTR 14290000u
#define OFF_FW    14370000u
#define OFF_FB    14450000u
#define OFF_ES    14500000u

// ---------------------------------------------------------------------------
// One-shot per-graph incoming-edge-list build (deterministic ascending order).
// ---------------------------------------------------------------------------
__global__ __launch_bounds__(128) void prep_kernel(
    const int* __restrict__ ei, const float* __restrict__ ea,
    unsigned short* __restrict__ elist, int* __restrict__ ecnt, float* __restrict__ sdeg)
{
  __shared__ unsigned char edstL[EPG];
  __shared__ float ewvL[EPG];
  const int g = blockIdx.x, t = threadIdx.x;
  const int nb = g * NPG;
  for (int e = t; e < EPG; e += 128) {
    int ge = g * EPG + e;
    edstL[e] = (unsigned char)(ei[ETOT + ge] - nb);
    ewvL[e] = ea[ge];
  }
  __syncthreads();
  if (t < NPG) {
    int cnt = 0; float s = 0.f;
    unsigned short* lp = elist + (size_t)(nb + t) * MAXDEG;
    for (int e = 0; e < EPG; e++) {
      if ((int)edstL[e] == t) {
        if (cnt < MAXDEG) lp[cnt] = (unsigned short)e;
        cnt++; s += ewvL[e];
      }
    }
    ecnt[nb + t] = cnt < MAXDEG ? cnt : MAXDEG;
    sdeg[nb + t] = s;
  }
}

// ---------------------------------------------------------------------------
// LEConv: out = segsum((a[src]-b[dst])*ew, dst) + x@w3 + b3
// Factored: agg[d] = sum_e ew*a[src_e]  -  b[d]*sdeg[d]
// 1024 threads (16 waves). Rows are wave-uniform -> x read direct from global
// (broadcast loads). Only `am` + edge metadata live in LDS (~69 KB).
// ---------------------------------------------------------------------------
template<int K, bool RELU>
__global__ __launch_bounds__(1024) void leconv_kernel(
    const float* __restrict__ xin, const int* __restrict__ ei, const float* __restrict__ ea,
    const unsigned short* __restrict__ elist, const int* __restrict__ ecnt, const float* __restrict__ sdeg,
    const float* __restrict__ w1, const float* __restrict__ b1,
    const float* __restrict__ w2, const float* __restrict__ w3, const float* __restrict__ b3,
    float* __restrict__ hout)
{
  __shared__ float am[NPG][HID];                 // 51.2 KB
  __shared__ unsigned char esrcL[EPG];           // 0.8 KB
  __shared__ float ewvL[EPG];                    // 3.2 KB
  __shared__ unsigned short elistL[NPG][MAXDEG]; // 12.8 KB
  __shared__ int ecntL[NPG];
  __shared__ float sdegL[NPG];

  const int g = blockIdx.x, t = threadIdx.x;
  const int nb = g * NPG;

  for (int e = t; e < EPG; e += 1024) {
    int ge = g * EPG + e;
    esrcL[e] = (unsigned char)(ei[ge] - nb);
    ewvL[e] = ea[ge];
  }
  for (int i = t; i < NPG * MAXDEG; i += 1024)
    ((unsigned short*)elistL)[i] = elist[(size_t)nb * MAXDEG + i];
  if (t < NPG) { ecntL[t] = ecnt[nb + t]; sdegL[t] = sdeg[nb + t]; }

  const int c = t & 127;          // output column
  const int grp = t >> 7;         // 0..7 ; rows r = grp + 8*i

  // a = x@w1 + b1
  float accA[13];
  const float bb = b1[c];
#pragma unroll
  for (int i = 0; i < 13; i++) accA[i] = bb;
  for (int k = 0; k < K; k += 4) {
    const float* wp = &w1[(size_t)k * HID + c];
    const float wa0 = wp[0], wa1 = wp[HID], wa2 = wp[2 * HID], wa3 = wp[3 * HID];
#pragma unroll
    for (int i = 0; i < 13; i++) {
      const int r = grp + 8 * i;
      if (r < NPG) {
        const float4 xv = *(const float4*)&xin[(size_t)(nb + r) * K + k];
        accA[i] += xv.x * wa0; accA[i] += xv.y * wa1; accA[i] += xv.z * wa2; accA[i] += xv.w * wa3;
      }
    }
  }
#pragma unroll
  for (int i = 0; i < 13; i++) { const int r = grp + 8 * i; if (r < NPG) am[r][c] = accA[i]; }
  __syncthreads();

  // b = x@w2, cdot = x@w3; out = agg - b*sdeg + cdot + b3
  float accB[13], accC[13];
#pragma unroll
  for (int i = 0; i < 13; i++) { accB[i] = 0.f; accC[i] = 0.f; }
  for (int k = 0; k < K; k += 4) {
    const float* p2 = &w2[(size_t)k * HID + c];
    const float u0 = p2[0], u1 = p2[HID], u2 = p2[2 * HID], u3 = p2[3 * HID];
    const float* p3 = &w3[(size_t)k * HID + c];
    const float r0 = p3[0], r1 = p3[HID], r2 = p3[2 * HID], r3 = p3[3 * HID];
#pragma unroll
    for (int i = 0; i < 13; i++) {
      const int r = grp + 8 * i;
      if (r < NPG) {
        const float4 xv = *(const float4*)&xin[(size_t)(nb + r) * K + k];
        accB[i] += xv.x * u0; accB[i] += xv.y * u1; accB[i] += xv.z * u2; accB[i] += xv.w * u3;
        accC[i] += xv.x * r0; accC[i] += xv.y * r1; accC[i] += xv.z * r2; accC[i] += xv.w * r3;
      }
    }
  }
  const float b3v = b3[c];
#pragma unroll
  for (int i = 0; i < 13; i++) {
    const int r = grp + 8 * i;
    if (r < NPG) {
      const int cn = ecntL[r]; const float sd = sdegL[r];
      float A0 = 0.f;
      for (int j = 0; j < cn; j++) {
        const int e = elistL[r][j];
        A0 += ewvL[e] * am[esrcL[e]][c];
      }
      float o = A0 - accB[i] * sd + accC[i] + b3v;
      if (RELU) o = fmaxf(o, 0.f);
      hout[(size_t)(nb + r) * HID + c] = o;
    }
  }
}

// ---------------------------------------------------------------------------
// Fused per-graph edge scorer. P = h@W1[0:128]+b1, Q = h@W1[128:256] in 64-col
// LDS chunks; per-edge score = sum relu(P[s]+Q[d])*w2 accumulated in FP64.
// 1024 threads; h read direct from global (wave-uniform rows). LDS ~56 KB.
// ---------------------------------------------------------------------------
__global__ __launch_bounds__(1024) void score_kernel(
    const float* __restrict__ h2, const int* __restrict__ ei,
    const float* __restrict__ w1, const float* __restrict__ b1,
    const float* __restrict__ w2, const float* __restrict__ b2,
    float* __restrict__ scores_ws, float* __restrict__ out_es)
{
  __shared__ float Pm[NPG][65];
  __shared__ float Qm[NPG][65];
  __shared__ unsigned char esrc[EPG];
  __shared__ unsigned char edst[EPG];
  __shared__ float w2l[512];

  const int g = blockIdx.x, t = threadIdx.x;
  const int nb = g * NPG;

  for (int e = t; e < EPG; e += 1024) {
    int ge = g * EPG + e;
    esrc[e] = (unsigned char)(ei[ge] - nb);
    edst[e] = (unsigned char)(ei[ETOT + ge] - nb);
  }
  if (t < 512) w2l[t] = w2[t];
  __syncthreads();

  const int c = t & 63, w = t >> 6;  // col-in-chunk, wave id; rows r = w + 16*i
  int sl = 0, dl = 0;
  if (t < EPG) { sl = esrc[t]; dl = edst[t]; }
  double a0 = 0.;

  for (int ch = 0; ch < 8; ++ch) {
    const int j0 = ch * 64;
    float accP[7], accQ[7];
    const float bp = b1[j0 + c];
#pragma unroll
    for (int i = 0; i < 7; i++) { accP[i] = bp; accQ[i] = 0.f; }
    for (int k = 0; k < HID; k += 4) {
      const float* wp = &w1[(size_t)k * 512 + j0 + c];
      const float p0 = wp[0], p1 = wp[512], p2v = wp[1024], p3v = wp[1536];
      const float* wq = &w1[(size_t)(HID + k) * 512 + j0 + c];
      const float q0 = wq[0], q1 = wq[512], q2v = wq[1024], q3v = wq[1536];
#pragma unroll
      for (int i = 0; i < 7; i++) {
        const int r = w + 16 * i;
        if (r < NPG) {
          const float4 hv = *(const float4*)&h2[(size_t)(nb + r) * HID + k];
          accP[i] += hv.x * p0; accP[i] += hv.y * p1; accP[i] += hv.z * p2v; accP[i] += hv.w * p3v;
          accQ[i] += hv.x * q0; accQ[i] += hv.y * q1; accQ[i] += hv.z * q2v; accQ[i] += hv.w * q3v;
        }
      }
    }
    __syncthreads();   // previous chunk's edge phase done reading Pm/Qm
#pragma unroll
    for (int i = 0; i < 7; i++) {
      const int r = w + 16 * i;
      if (r < NPG) { Pm[r][c] = accP[i]; Qm[r][c] = accQ[i]; }
    }
    __syncthreads();

    if (t < EPG) {
      double aa = 0.;
      for (int j = 0; j < 64; j++) {
        const float p = Pm[sl][j] + Qm[dl][j];
        aa += (double)fmaxf(p, 0.f) * (double)w2l[j0 + j];
      }
      a0 += aa;
    }
  }

  if (t < EPG) {
    const float sc = (float)(a0 + (double)b2[0]);
    const int ge = g * EPG + t;
    scores_ws[ge] = sc; out_es[ge] = sc;
  }
}

// ---------------------------------------------------------------------------
// Per-graph stable descending sort of 800 scores (bitonic on packed u64 keys),
// top-K split, presence marking, local relabel ranks.
// ---------------------------------------------------------------------------
__global__ __launch_bounds__(256, 1) void sort_kernel(
    const float* __restrict__ scores, const int* __restrict__ ei,
    int* __restrict__ keptEid, int* __restrict__ dropEid,
    int* __restrict__ cLocal, int* __restrict__ fLocal,
    int* __restrict__ cCount, int* __restrict__ fCount)
{
  __shared__ unsigned long long keys[1024];
  __shared__ int cpres[NPG];
  __shared__ int fpres[NPG];
  const int g = blockIdx.x, t = threadIdx.x;
  const int nb = g * NPG;

  for (int i = t; i < 1024; i += 256) {
    unsigned long long kk;
    if (i < EPG) {
      const float sc = scores[g * EPG + i];
      const unsigned int b = __float_as_uint(sc);
      const unsigned int m = (b & 0x80000000u) ? (~b) : (b | 0x80000000u); // ascending map
      const unsigned int k1 = ~m;                                          // descending score
      kk = ((unsigned long long)k1 << 32) | (unsigned int)i;               // idx asc tiebreak
    } else {
      kk = 0xFFFFFFFFFFFFFFFFull;
    }
    keys[i] = kk;
  }
  for (int i = t; i < NPG; i += 256) { cpres[i] = 0; fpres[i] = 0; }
  __syncthreads();

  for (int k = 2; k <= 1024; k <<= 1) {
    for (int j = k >> 1; j > 0; j >>= 1) {
      for (int i = t; i < 1024; i += 256) {
        const int l = i ^ j;
        if (l > i) {
          const bool up = ((i & k) == 0);
          const unsigned long long va = keys[i], vb = keys[l];
          if ((va > vb) == up) { keys[i] = vb; keys[l] = va; }
        }
      }
      __syncthreads();
    }
  }

  for (int r = t; r < EPG; r += 256) {
    const int el = (int)(unsigned int)keys[r];
    const int ge = g * EPG + el;
    const int sl = ei[ge] - nb, dl = ei[ETOT + ge] - nb;
    if (r < KKEEP) {
      keptEid[g * KKEEP + r] = ge;
      cpres[sl] = 1; cpres[dl] = 1;
    } else {
      dropEid[g * KDROP + (r - KKEEP)] = ge;
      fpres[sl] = 1; fpres[dl] = 1;
    }
  }
  __syncthreads();

  if (t == 0) {
    int cc = 0;
    for (int v = 0; v < NPG; v++) { const int p = cpres[v]; cLocal[nb + v] = p ? cc : -1; cc += p; }
    cCount[g] = cc;
  }
  if (t == 64) {
    int fc = 0;
    for (int v = 0; v < NPG; v++) { const int p = fpres[v]; fLocal[nb + v] = p ? fc : -1; fc += p; }
    fCount[g] = fc;
  }
}

// exclusive scan of 500 per-graph unique counts (both sides) in one block
__global__ __launch_bounds__(512) void offsets_kernel(
    const int* __restrict__ cCount, const int* __restrict__ fCount,
    int* __restrict__ cOff, int* __restrict__ fOff)
{
  __shared__ int sc[512];
  __shared__ int sf[512];
  const int t = threadIdx.x;
  const int c0 = (t < NG) ? cCount[t] : 0;
  const int f0 = (t < NG) ? fCount[t] : 0;
  sc[t] = c0; sf[t] = f0;
  __syncthreads();
  for (int off = 1; off < 512; off <<= 1) {
    const int ac = (t >= off) ? sc[t - off] : 0;
    const int af = (t >= off) ? sf[t - off] : 0;
    __syncthreads();
    sc[t] += ac; sf[t] += af;
    __syncthreads();
  }
  if (t < NG) { cOff[t] = sc[t] - c0; fOff[t] = sf[t] - f0; }
  if (t == NG - 1) { cOff[NG] = sc[t]; fOff[NG] = sf[t]; }
}

// scatter h rows of present nodes into compacted c_x / f_x, write node_idx & batch
__global__ __launch_bounds__(256) void scatter_kernel(
    const float* __restrict__ h2, const int* __restrict__ cLocal, const int* __restrict__ fLocal,
    const int* __restrict__ cOff, const int* __restrict__ fOff,
    int* __restrict__ nodeIdxC, int* __restrict__ nodeIdxF, float* __restrict__ out)
{
  const int tid = blockIdx.x * 256 + threadIdx.x;
  if (tid >= 2 * NTOT * 32) return;
  const int side = tid >= NTOT * 32 ? 1 : 0;
  const int rem = tid - side * NTOT * 32;
  const int v = rem >> 5, q = rem & 31;
  const int loc = side ? fLocal[v] : cLocal[v];
  if (loc < 0) return;
  const int g = v / NPG;
  const int pos = (side ? fOff[g] : cOff[g]) + loc;
  const float4* srcv = (const float4*)(h2 + (size_t)v * HID);
  float4* dstv = (float4*)(out + (side ? OFF_FX : OFF_CX) + (size_t)pos * HID);
  dstv[q] = srcv[q];
  if (q == 0) {
    (side ? nodeIdxF : nodeIdxC)[v] = pos;
    out[(side ? OFF_FB : OFF_CB) + pos] = (float)g;
  }
}

// zero-fill pad rows (unique count < N) and batch = -1
__global__ __launch_bounds__(256) void fill_kernel(
    const int* __restrict__ cOff, const int* __restrict__ fOff, float* __restrict__ out)
{
  const int tid = blockIdx.x * 256 + threadIdx.x;
  if (tid >= 2 * NTOT * 32) return;
  const int side = tid >= NTOT * 32 ? 1 : 0;
  const int rem = tid - side * NTOT * 32;
  const int r = rem >> 5, q = rem & 31;
  const int total = side ? fOff[NG] : cOff[NG];
  if (r < total) return;
  float4 z; z.x = 0.f; z.y = 0.f; z.z = 0.f; z.w = 0.f;
  ((float4*)(out + (side ? OFF_FX : OFF_CX)))[(size_t)r * 32 + q] = z;
  if (q == 0) out[(side ? OFF_FB : OFF_CB) + r] = -1.0f;
}

// remapped edge indices + gathered attr/weight outputs
__global__ __launch_bounds__(256) void edgeout_kernel(
    const int* __restrict__ ei, const float* __restrict__ ea, const float* __restrict__ scores,
    const int* __restrict__ keptEid, const int* __restrict__ dropEid,
    const int* __restrict__ nodeIdxC, const int* __restrict__ nodeIdxF, float* __restrict__ out)
{
  const int tid = blockIdx.x * 256 + threadIdx.x;
  if (tid >= ETOT) return;
  if (tid < NG * KKEEP) {
    const int ge = keptEid[tid];
    out[OFF_CEI + tid] = (float)nodeIdxC[ei[ge]];
    out[OFF_CEI + 320000 + tid] = (float)nodeIdxC[ei[ETOT + ge]];
    out[OFF_CATTR + tid] = ea[ge];
    out[OFF_CW + tid] = scores[ge];
  } else {
    const int i = tid - NG * KKEEP;
    const int ge = dropEid[i];
    out[OFF_FEI + i] = (float)nodeIdxF[ei[ge]];
    out[OFF_FEI + 80000 + i] = (float)nodeIdxF[ei[ETOT + ge]];
    out[OFF_FATTR + i] = ea[ge];
    out[OFF_FW + i] = -scores[ge];
  }
}

extern "C" void kernel_launch(void* const* d_in, const int* in_sizes, int n_in,
                              void* d_out, int out_size, void* d_ws, size_t ws_size,
                              hipStream_t stream) {
  const float* x    = (const float*)d_in[0];
  const int*   ei   = (const int*)d_in[1];
  const float* ea   = (const float*)d_in[2];
  const float* c1w1 = (const float*)d_in[4];
  const float* c1b1 = (const float*)d_in[5];
  const float* c1w2 = (const float*)d_in[6];
  const float* c1w3 = (const float*)d_in[7];
  const float* c1b3 = (const float*)d_in[8];
  const float* c2w1 = (const float*)d_in[9];
  const float* c2b1 = (const float*)d_in[10];
  const float* c2w2 = (const float*)d_in[11];
  const float* c2w3 = (const float*)d_in[12];
  const float* c2b3 = (const float*)d_in[13];
  const float* mw1  = (const float*)d_in[14];
  const float* mb1  = (const float*)d_in[15];
  const float* mw2  = (const float*)d_in[16];
  const float* mb2  = (const float*)d_in[17];
  float* out = (float*)d_out;

  char* p = (char*)d_ws;
  auto carve = [&](size_t bytes) { void* r = (void*)p; p += (bytes + 255) & ~(size_t)255; return r; };
  float* h1      = (float*)carve((size_t)NTOT * HID * 4);
  float* h2      = (float*)carve((size_t)NTOT * HID * 4);
  float* scores  = (float*)carve((size_t)ETOT * 4);
  int* keptEid   = (int*)carve((size_t)NG * KKEEP * 4);
  int* dropEid   = (int*)carve((size_t)NG * KDROP * 4);
  int* cLocal    = (int*)carve((size_t)NTOT * 4);
  int* fLocal    = (int*)carve((size_t)NTOT * 4);
  int* cCount    = (int*)carve((size_t)NG * 4);
  int* fCount    = (int*)carve((size_t)NG * 4);
  int* cOff      = (int*)carve((size_t)(NG + 1) * 4);
  int* fOff      = (int*)carve((size_t)(NG + 1) * 4);
  int* nodeIdxC  = (int*)carve((size_t)NTOT * 4);
  int* nodeIdxF  = (int*)carve((size_t)NTOT * 4);
  unsigned short* elist = (unsigned short*)carve((size_t)NTOT * MAXDEG * 2);
  int* ecnt      = (int*)carve((size_t)NTOT * 4);
  float* sdeg    = (float*)carve((size_t)NTOT * 4);

  prep_kernel<<<NG, 128, 0, stream>>>(ei, ea, elist, ecnt, sdeg);
  leconv_kernel<INDIM, true><<<NG, 1024, 0, stream>>>(x, ei, ea, elist, ecnt, sdeg, c1w1, c1b1, c1w2, c1w3, c1b3, h1);
  leconv_kernel<HID, false><<<NG, 1024, 0, stream>>>(h1, ei, ea, elist, ecnt, sdeg, c2w1, c2b1, c2w2, c2w3, c2b3, h2);
  score_kernel<<<NG, 1024, 0, stream>>>(h2, ei, mw1, mb1, mw2, mb2, scores, out + OFF_ES);
  sort_kernel<<<NG, 256, 0, stream>>>(scores, ei, keptEid, dropEid, cLocal, fLocal, cCount, fCount);
  offsets_kernel<<<1, 512, 0, stream>>>(cCount, fCount, cOff, fOff);
  const int sc_threads = 2 * NTOT * 32;
  scatter_kernel<<<(sc_threads + 255) / 256, 256, 0, stream>>>(h2, cLocal, fLocal, cOff, fOff, nodeIdxC, nodeIdxF, out);
  fill_kernel<<<(sc_threads + 255) / 256, 256, 0, stream>>>(cOff, fOff, out);
  edgeout_kernel<<<(ETOT + 255) / 256, 256, 0, stream>>>(ei, ea, scores, keptEid, dropEid, nodeIdxC, nodeIdxF, out);
}

// Round 3
// 913.211 us; speedup vs baseline: 1.2775x; 1.2580x over previous
//
#include <hip/hip_runtime.h>

#define NG 500
#define NPG 100
#define EPG 800
#define INDIM 64
#define HID 128
#define ETOT (NG*EPG)
#define NTOT (NG*NPG)
#define KKEEP 640
#define KDROP 160
#define MAXDEG 64

// output section offsets (in floats)
#define OFF_CX    0u
#define OFF_CEI   6400000u
#define OFF_CATTR 7040000u
#define OFF_CW    7360000u
#define OFF_CB    7680000u
#define OFF_FX    7730000u
#define OFF_FEI   14130000u
#define OFF_FATTR 14290000u
#define OFF_FW    14370000u
#define OFF_FB    14450000u
#define OFF_ES    14500000u

// ---------------------------------------------------------------------------
// prep: per-dst incoming edge lists as (ew, src) pairs + weighted degree.
// Deterministic ascending-edge order.
// ---------------------------------------------------------------------------
__global__ __launch_bounds__(128) void prep_kernel(
    const int* __restrict__ ei, const float* __restrict__ ea,
    float2* __restrict__ elist2, int* __restrict__ ecnt, float* __restrict__ sdeg)
{
  __shared__ unsigned char esrcL[EPG];
  __shared__ unsigned char edstL[EPG];
  __shared__ float ewvL[EPG];
  const int g = blockIdx.x, t = threadIdx.x;
  const int nb = g * NPG;
  for (int e = t; e < EPG; e += 128) {
    int ge = g * EPG + e;
    esrcL[e] = (unsigned char)(ei[ge] - nb);
    edstL[e] = (unsigned char)(ei[ETOT + ge] - nb);
    ewvL[e] = ea[ge];
  }
  __syncthreads();
  if (t < NPG) {
    int cnt = 0; float s = 0.f;
    float2* lp = elist2 + (size_t)(nb + t) * MAXDEG;
    for (int e = 0; e < EPG; e++) {
      if ((int)edstL[e] == t) {
        if (cnt < MAXDEG) lp[cnt] = make_float2(ewvL[e], __int_as_float((int)esrcL[e]));
        cnt++; s += ewvL[e];
      }
    }
    ecnt[nb + t] = cnt < MAXDEG ? cnt : MAXDEG;
    sdeg[nb + t] = s;
  }
}

// ---------------------------------------------------------------------------
// preagg: y[d] = sum_e ew * x[src_e]   (K-dim pre-aggregation, per graph)
// ---------------------------------------------------------------------------
template<int K>
__global__ __launch_bounds__(512) void preagg_kernel(
    const float* __restrict__ xin, const float2* __restrict__ elist2,
    const int* __restrict__ ecnt, float* __restrict__ y)
{
  __shared__ float xt[NPG][K];
  const int g = blockIdx.x, t = threadIdx.x;
  const int nb = g * NPG;
  for (int i = t; i < NPG * K / 4; i += 512)
    ((float4*)xt)[i] = ((const float4*)(xin + (size_t)nb * K))[i];
  __syncthreads();
  const int c = t % K, grp = t / K;
  const int NGRP = 512 / K;
  for (int d = grp; d < NPG; d += NGRP) {
    const int cn = ecnt[nb + d];
    const float2* lp = elist2 + (size_t)(nb + d) * MAXDEG;
    float acc = 0.f;
    for (int j = 0; j < cn; j++) {
      float2 p = lp[j];
      acc += p.x * xt[__float_as_int(p.y)][c];
    }
    y[(size_t)(nb + d) * K + c] = acc;
  }
}

// ---------------------------------------------------------------------------
// conv GEMM: h = [y | x | sd*x] @ [w1; w3; -w2] + sd*b1 + b3  (opt relu)
// M-tile 128, 256 threads, 8x8 register tiles, B' staged in 32KB LDS chunks.
// ---------------------------------------------------------------------------
template<int K, bool RELU>
__global__ __launch_bounds__(256) void conv_gemm_kernel(
    const float* __restrict__ y, const float* __restrict__ xin, const float* __restrict__ sdeg,
    const float* __restrict__ w1, const float* __restrict__ w2, const float* __restrict__ w3,
    const float* __restrict__ b1, const float* __restrict__ b3,
    float* __restrict__ hout)
{
  __shared__ float wl[64][HID];   // 32KB B' chunk
  const int t = threadIdx.x;
  const int m0 = blockIdx.x * 128;
  const int tc = t % 16;          // cols tc*4..+3 and 64+tc*4..+3 (2-way-free LDS)
  const int tr = t / 16;          // rows m0 + tr*8 .. +7
  float acc[8][8];
#pragma unroll
  for (int i = 0; i < 8; i++)
#pragma unroll
    for (int j = 0; j < 8; j++) acc[i][j] = 0.f;

  int rowc[8]; float sdv[8];
#pragma unroll
  for (int i = 0; i < 8; i++) {
    int r = m0 + tr * 8 + i;
    rowc[i] = r < NTOT ? r : NTOT - 1;
    sdv[i] = sdeg[rowc[i]];
  }
  const int NCH = (3 * K) / 64;
  for (int ch = 0; ch < NCH; ++ch) {
    __syncthreads();
    for (int i = t; i < 64 * HID / 4; i += 256) {
      int kk = i / 32, q = i % 32;
      int kr = ch * 64 + kk;
      int seg = kr / K; int sr = kr % K;
      const float* wp = seg == 0 ? w1 : (seg == 1 ? w3 : w2);
      float4 v = *(const float4*)(wp + (size_t)sr * HID + q * 4);
      if (seg == 2) { v.x = -v.x; v.y = -v.y; v.z = -v.z; v.w = -v.w; }
      *(float4*)&wl[kk][q * 4] = v;
    }
    __syncthreads();
    const int seg = (ch * 64) / K;
    const int kb = (ch * 64) % K;
    for (int k4 = 0; k4 < 16; ++k4) {
      float4 a4[8];
#pragma unroll
      for (int i = 0; i < 8; i++) {
        const float* src = (seg == 0 ? y : xin) + (size_t)rowc[i] * K + kb + k4 * 4;
        float4 v = *(const float4*)src;
        if (seg == 2) { float s = sdv[i]; v.x *= s; v.y *= s; v.z *= s; v.w *= s; }
        a4[i] = v;
      }
#pragma unroll
      for (int kk = 0; kk < 4; kk++) {
        float wv0[4], wv1[4];
        *(float4*)wv0 = *(const float4*)&wl[k4 * 4 + kk][tc * 4];
        *(float4*)wv1 = *(const float4*)&wl[k4 * 4 + kk][64 + tc * 4];
#pragma unroll
        for (int i = 0; i < 8; i++) {
          const float av = (&a4[i].x)[kk];
#pragma unroll
          for (int j = 0; j < 4; j++) {
            acc[i][j]     += av * wv0[j];
            acc[i][4 + j] += av * wv1[j];
          }
        }
      }
    }
  }
#pragma unroll
  for (int i = 0; i < 8; i++) {
    const int r = m0 + tr * 8 + i;
    if (r < NTOT) {
      float4 o0, o1;
#pragma unroll
      for (int j = 0; j < 4; j++) {
        float c0 = acc[i][j]     + sdv[i] * b1[tc * 4 + j]      + b3[tc * 4 + j];
        float c1 = acc[i][4 + j] + sdv[i] * b1[64 + tc * 4 + j] + b3[64 + tc * 4 + j];
        if (RELU) { c0 = fmaxf(c0, 0.f); c1 = fmaxf(c1, 0.f); }
        (&o0.x)[j] = c0; (&o1.x)[j] = c1;
      }
      float* op = hout + (size_t)r * HID;
      *(float4*)(op + tc * 4) = o0;
      *(float4*)(op + 64 + tc * 4) = o1;
    }
  }
}

// ---------------------------------------------------------------------------
// score: 2-graph blocks. Per 64-col chunk: stage W1a/W1b chunk in LDS,
// GEMM (8 rows x 2 cols per thread) -> Pl/Ql [200][64], then edge phase with
// pair-rotated j (2-way-free LDS). FP64 score accumulation.
// ---------------------------------------------------------------------------
__global__ __launch_bounds__(1024) void score_kernel(
    const float* __restrict__ h2, const int* __restrict__ ei,
    const float* __restrict__ mw1, const float* __restrict__ mb1,
    const float* __restrict__ mw2, const float* __restrict__ mb2,
    float* __restrict__ scores_ws, float* __restrict__ out_es)
{
  __shared__ float Pl[200][64];
  __shared__ float Ql[200][64];
  __shared__ float wl[HID][64];
  __shared__ float w2l[64];
  __shared__ unsigned char esrcL[2 * EPG];
  __shared__ unsigned char edstL[2 * EPG];

  const int b = blockIdx.x, t = threadIdx.x;
  const int g0 = 2 * b;
  const int rowbase = b * 200;

  for (int e = t; e < 2 * EPG; e += 1024) {
    int gi = e / EPG, el = e - gi * EPG;
    int ge = (g0 + gi) * EPG + el;
    esrcL[e] = (unsigned char)(ei[ge] - (g0 + gi) * NPG);
    edstL[e] = (unsigned char)(ei[ETOT + ge] - (g0 + gi) * NPG);
  }

  const int tc = t % 32;   // cols tc*2, tc*2+1
  const int tr = t / 32;   // row group (tr<25): rows tr*8..+7 of 200
  int sl0 = 0, dl0 = 0, sl1 = 0, dl1 = 0;
  double acc0 = 0., acc1 = 0.;
  const int pr = (t >> 1) & 31;

  for (int ch = 0; ch < 8; ++ch) {
    __syncthreads();  // previous edge phase done (and edge staging on ch=0)
    if (ch == 0 && t < EPG) {
      sl0 = esrcL[t];        dl0 = edstL[t];
      sl1 = 100 + esrcL[EPG + t]; dl1 = 100 + edstL[EPG + t];
    }
    // stage W1a chunk
    for (int i = t; i < HID * 16; i += 1024) {
      int k = i / 16, q = i % 16;
      *(float4*)&wl[k][q * 4] = *(const float4*)(mw1 + (size_t)k * 512 + ch * 64 + q * 4);
    }
    __syncthreads();
    if (tr < 25) {
      float a0[8], a1[8];
      const float bp0 = mb1[ch * 64 + tc * 2], bp1 = mb1[ch * 64 + tc * 2 + 1];
#pragma unroll
      for (int i = 0; i < 8; i++) { a0[i] = bp0; a1[i] = bp1; }
      for (int k4 = 0; k4 < 32; ++k4) {
        float4 a4[8];
#pragma unroll
        for (int i = 0; i < 8; i++)
          a4[i] = *(const float4*)(h2 + (size_t)(rowbase + tr * 8 + i) * HID + k4 * 4);
#pragma unroll
        for (int kk = 0; kk < 4; kk++) {
          const float2 wv = *(const float2*)&wl[k4 * 4 + kk][tc * 2];
#pragma unroll
          for (int i = 0; i < 8; i++) {
            const float av = (&a4[i].x)[kk];
            a0[i] += av * wv.x; a1[i] += av * wv.y;
          }
        }
      }
#pragma unroll
      for (int i = 0; i < 8; i++)
        *(float2*)&Pl[tr * 8 + i][tc * 2] = make_float2(a0[i], a1[i]);
    }
    __syncthreads();  // wl reads + Pl writes done
    // stage W1b chunk + w2 chunk
    for (int i = t; i < HID * 16; i += 1024) {
      int k = i / 16, q = i % 16;
      *(float4*)&wl[k][q * 4] = *(const float4*)(mw1 + (size_t)(HID + k) * 512 + ch * 64 + q * 4);
    }
    if (t < 16) *(float4*)&w2l[t * 4] = *(const float4*)(mw2 + ch * 64 + t * 4);
    __syncthreads();
    if (tr < 25) {
      float a0[8], a1[8];
#pragma unroll
      for (int i = 0; i < 8; i++) { a0[i] = 0.f; a1[i] = 0.f; }
      for (int k4 = 0; k4 < 32; ++k4) {
        float4 a4[8];
#pragma unroll
        for (int i = 0; i < 8; i++)
          a4[i] = *(const float4*)(h2 + (size_t)(rowbase + tr * 8 + i) * HID + k4 * 4);
#pragma unroll
        for (int kk = 0; kk < 4; kk++) {
          const float2 wv = *(const float2*)&wl[k4 * 4 + kk][tc * 2];
#pragma unroll
          for (int i = 0; i < 8; i++) {
            const float av = (&a4[i].x)[kk];
            a0[i] += av * wv.x; a1[i] += av * wv.y;
          }
        }
      }
#pragma unroll
      for (int i = 0; i < 8; i++)
        *(float2*)&Ql[tr * 8 + i][tc * 2] = make_float2(a0[i], a1[i]);
    }
    __syncthreads();  // Ql + w2l ready
    if (t < EPG) {
#pragma unroll 4
      for (int i = 0; i < 32; ++i) {
        const int j = (((pr + i) & 31) * 2);
        const float2 p0 = *(const float2*)&Pl[sl0][j];
        const float2 q0 = *(const float2*)&Ql[dl0][j];
        const float2 p1 = *(const float2*)&Pl[sl1][j];
        const float2 q1 = *(const float2*)&Ql[dl1][j];
        const float2 wv = *(const float2*)&w2l[j];
        const float s0 = fmaxf(p0.x + q0.x, 0.f) * wv.x + fmaxf(p0.y + q0.y, 0.f) * wv.y;
        const float s1 = fmaxf(p1.x + q1.x, 0.f) * wv.x + fmaxf(p1.y + q1.y, 0.f) * wv.y;
        acc0 += (double)s0; acc1 += (double)s1;
      }
    }
  }
  if (t < EPG) {
    const double b2v = (double)mb2[0];
    const float s0 = (float)(acc0 + b2v);
    const float s1 = (float)(acc1 + b2v);
    const int ge0 = g0 * EPG + t, ge1 = (g0 + 1) * EPG + t;
    scores_ws[ge0] = s0; out_es[ge0] = s0;
    scores_ws[ge1] = s1; out_es[ge1] = s1;
  }
}

// ---------------------------------------------------------------------------
// Per-graph stable descending sort (bitonic on packed u64), top-K split,
// presence marking, local relabel ranks.
// ---------------------------------------------------------------------------
__global__ __launch_bounds__(256, 1) void sort_kernel(
    const float* __restrict__ scores, const int* __restrict__ ei,
    int* __restrict__ keptEid, int* __restrict__ dropEid,
    int* __restrict__ cLocal, int* __restrict__ fLocal,
    int* __restrict__ cCount, int* __restrict__ fCount)
{
  __shared__ unsigned long long keys[1024];
  __shared__ int cpres[NPG];
  __shared__ int fpres[NPG];
  const int g = blockIdx.x, t = threadIdx.x;
  const int nb = g * NPG;

  for (int i = t; i < 1024; i += 256) {
    unsigned long long kk;
    if (i < EPG) {
      const float sc = scores[g * EPG + i];
      const unsigned int bb = __float_as_uint(sc);
      const unsigned int m = (bb & 0x80000000u) ? (~bb) : (bb | 0x80000000u);
      const unsigned int k1 = ~m;
      kk = ((unsigned long long)k1 << 32) | (unsigned int)i;
    } else {
      kk = 0xFFFFFFFFFFFFFFFFull;
    }
    keys[i] = kk;
  }
  for (int i = t; i < NPG; i += 256) { cpres[i] = 0; fpres[i] = 0; }
  __syncthreads();

  for (int k = 2; k <= 1024; k <<= 1) {
    for (int j = k >> 1; j > 0; j >>= 1) {
      for (int i = t; i < 1024; i += 256) {
        const int l = i ^ j;
        if (l > i) {
          const bool up = ((i & k) == 0);
          const unsigned long long va = keys[i], vb = keys[l];
          if ((va > vb) == up) { keys[i] = vb; keys[l] = va; }
        }
      }
      __syncthreads();
    }
  }

  for (int r = t; r < EPG; r += 256) {
    const int el = (int)(unsigned int)keys[r];
    const int ge = g * EPG + el;
    const int sl = ei[ge] - nb, dl = ei[ETOT + ge] - nb;
    if (r < KKEEP) {
      keptEid[g * KKEEP + r] = ge;
      cpres[sl] = 1; cpres[dl] = 1;
    } else {
      dropEid[g * KDROP + (r - KKEEP)] = ge;
      fpres[sl] = 1; fpres[dl] = 1;
    }
  }
  __syncthreads();

  if (t == 0) {
    int cc = 0;
    for (int v = 0; v < NPG; v++) { const int p = cpres[v]; cLocal[nb + v] = p ? cc : -1; cc += p; }
    cCount[g] = cc;
  }
  if (t == 64) {
    int fc = 0;
    for (int v = 0; v < NPG; v++) { const int p = fpres[v]; fLocal[nb + v] = p ? fc : -1; fc += p; }
    fCount[g] = fc;
  }
}

__global__ __launch_bounds__(512) void offsets_kernel(
    const int* __restrict__ cCount, const int* __restrict__ fCount,
    int* __restrict__ cOff, int* __restrict__ fOff)
{
  __shared__ int sc[512];
  __shared__ int sf[512];
  const int t = threadIdx.x;
  const int c0 = (t < NG) ? cCount[t] : 0;
  const int f0 = (t < NG) ? fCount[t] : 0;
  sc[t] = c0; sf[t] = f0;
  __syncthreads();
  for (int off = 1; off < 512; off <<= 1) {
    const int ac = (t >= off) ? sc[t - off] : 0;
    const int af = (t >= off) ? sf[t - off] : 0;
    __syncthreads();
    sc[t] += ac; sf[t] += af;
    __syncthreads();
  }
  if (t < NG) { cOff[t] = sc[t] - c0; fOff[t] = sf[t] - f0; }
  if (t == NG - 1) { cOff[NG] = sc[t]; fOff[NG] = sf[t]; }
}

__global__ __launch_bounds__(256) void scatter_kernel(
    const float* __restrict__ h2, const int* __restrict__ cLocal, const int* __restrict__ fLocal,
    const int* __restrict__ cOff, const int* __restrict__ fOff,
    int* __restrict__ nodeIdxC, int* __restrict__ nodeIdxF, float* __restrict__ out)
{
  const int tid = blockIdx.x * 256 + threadIdx.x;
  if (tid >= 2 * NTOT * 32) return;
  const int side = tid >= NTOT * 32 ? 1 : 0;
  const int rem = tid - side * NTOT * 32;
  const int v = rem >> 5, q = rem & 31;
  const int loc = side ? fLocal[v] : cLocal[v];
  if (loc < 0) return;
  const int g = v / NPG;
  const int pos = (side ? fOff[g] : cOff[g]) + loc;
  const float4* srcv = (const float4*)(h2 + (size_t)v * HID);
  float4* dstv = (float4*)(out + (side ? OFF_FX : OFF_CX) + (size_t)pos * HID);
  dstv[q] = srcv[q];
  if (q == 0) {
    (side ? nodeIdxF : nodeIdxC)[v] = pos;
    out[(side ? OFF_FB : OFF_CB) + pos] = (float)g;
  }
}

__global__ __launch_bounds__(256) void fill_kernel(
    const int* __restrict__ cOff, const int* __restrict__ fOff, float* __restrict__ out)
{
  const int tid = blockIdx.x * 256 + threadIdx.x;
  if (tid >= 2 * NTOT * 32) return;
  const int side = tid >= NTOT * 32 ? 1 : 0;
  const int rem = tid - side * NTOT * 32;
  const int r = rem >> 5, q = rem & 31;
  const int total = side ? fOff[NG] : cOff[NG];
  if (r < total) return;
  float4 z; z.x = 0.f; z.y = 0.f; z.z = 0.f; z.w = 0.f;
  ((float4*)(out + (side ? OFF_FX : OFF_CX)))[(size_t)r * 32 + q] = z;
  if (q == 0) out[(side ? OFF_FB : OFF_CB) + r] = -1.0f;
}

__global__ __launch_bounds__(256) void edgeout_kernel(
    const int* __restrict__ ei, const float* __restrict__ ea, const float* __restrict__ scores,
    const int* __restrict__ keptEid, const int* __restrict__ dropEid,
    const int* __restrict__ nodeIdxC, const int* __restrict__ nodeIdxF, float* __restrict__ out)
{
  const int tid = blockIdx.x * 256 + threadIdx.x;
  if (tid >= ETOT) return;
  if (tid < NG * KKEEP) {
    const int ge = keptEid[tid];
    out[OFF_CEI + tid] = (float)nodeIdxC[ei[ge]];
    out[OFF_CEI + 320000 + tid] = (float)nodeIdxC[ei[ETOT + ge]];
    out[OFF_CATTR + tid] = ea[ge];
    out[OFF_CW + tid] = scores[ge];
  } else {
    const int i = tid - NG * KKEEP;
    const int ge = dropEid[i];
    out[OFF_FEI + i] = (float)nodeIdxF[ei[ge]];
    out[OFF_FEI + 80000 + i] = (float)nodeIdxF[ei[ETOT + ge]];
    out[OFF_FATTR + i] = ea[ge];
    out[OFF_FW + i] = -scores[ge];
  }
}

extern "C" void kernel_launch(void* const* d_in, const int* in_sizes, int n_in,
                              void* d_out, int out_size, void* d_ws, size_t ws_size,
                              hipStream_t stream) {
  const float* x    = (const float*)d_in[0];
  const int*   ei   = (const int*)d_in[1];
  const float* ea   = (const float*)d_in[2];
  const float* c1w1 = (const float*)d_in[4];
  const float* c1b1 = (const float*)d_in[5];
  const float* c1w2 = (const float*)d_in[6];
  const float* c1w3 = (const float*)d_in[7];
  const float* c1b3 = (const float*)d_in[8];
  const float* c2w1 = (const float*)d_in[9];
  const float* c2b1 = (const float*)d_in[10];
  const float* c2w2 = (const float*)d_in[11];
  const float* c2w3 = (const float*)d_in[12];
  const float* c2b3 = (const float*)d_in[13];
  const float* mw1  = (const float*)d_in[14];
  const float* mb1  = (const float*)d_in[15];
  const float* mw2  = (const float*)d_in[16];
  const float* mb2  = (const float*)d_in[17];
  float* out = (float*)d_out;

  char* p = (char*)d_ws;
  auto carve = [&](size_t bytes) { void* r = (void*)p; p += (bytes + 255) & ~(size_t)255; return r; };
  float* h1      = (float*)carve((size_t)NTOT * HID * 4);
  float* h2      = (float*)carve((size_t)NTOT * HID * 4);
  float* ybuf    = (float*)carve((size_t)NTOT * HID * 4);
  float* scores  = (float*)carve((size_t)ETOT * 4);
  int* keptEid   = (int*)carve((size_t)NG * KKEEP * 4);
  int* dropEid   = (int*)carve((size_t)NG * KDROP * 4);
  int* cLocal    = (int*)carve((size_t)NTOT * 4);
  int* fLocal    = (int*)carve((size_t)NTOT * 4);
  int* cCount    = (int*)carve((size_t)NG * 4);
  int* fCount    = (int*)carve((size_t)NG * 4);
  int* cOff      = (int*)carve((size_t)(NG + 1) * 4);
  int* fOff      = (int*)carve((size_t)(NG + 1) * 4);
  int* nodeIdxC  = (int*)carve((size_t)NTOT * 4);
  int* nodeIdxF  = (int*)carve((size_t)NTOT * 4);
  float2* elist2 = (float2*)carve((size_t)NTOT * MAXDEG * 8);
  int* ecnt      = (int*)carve((size_t)NTOT * 4);
  float* sdeg    = (float*)carve((size_t)NTOT * 4);

  const int MT = (NTOT + 127) / 128;

  prep_kernel<<<NG, 128, 0, stream>>>(ei, ea, elist2, ecnt, sdeg);
  preagg_kernel<INDIM><<<NG, 512, 0, stream>>>(x, elist2, ecnt, ybuf);
  conv_gemm_kernel<INDIM, true><<<MT, 256, 0, stream>>>(ybuf, x, sdeg, c1w1, c1w2, c1w3, c1b1, c1b3, h1);
  preagg_kernel<HID><<<NG, 512, 0, stream>>>(h1, elist2, ecnt, ybuf);
  conv_gemm_kernel<HID, false><<<MT, 256, 0, stream>>>(ybuf, h1, sdeg, c2w1, c2w2, c2w3, c2b1, c2b3, h2);
  score_kernel<<<NG / 2, 1024, 0, stream>>>(h2, ei, mw1, mb1, mw2, mb2, scores, out + OFF_ES);
  sort_kernel<<<NG, 256, 0, stream>>>(scores, ei, keptEid, dropEid, cLocal, fLocal, cCount, fCount);
  offsets_kernel<<<1, 512, 0, stream>>>(cCount, fCount, cOff, fOff);
  const int sc_threads = 2 * NTOT * 32;
  scatter_kernel<<<(sc_threads + 255) / 256, 256, 0, stream>>>(h2, cLocal, fLocal, cOff, fOff, nodeIdxC, nodeIdxF, out);
  fill_kernel<<<(sc_threads + 255) / 256, 256, 0, stream>>>(cOff, fOff, out);
  edgeout_kernel<<<(ETOT + 255) / 256, 256, 0, stream>>>(ei, ea, scores, keptEid, dropEid, nodeIdxC, nodeIdxF, out);
}

// Round 6
// 833.106 us; speedup vs baseline: 1.4003x; 1.0962x over previous
//
#include <hip/hip_runtime.h>

#define NG 500
#define NPG 100
#define EPG 800
#define INDIM 64
#define HID 128
#define ETOT (NG*EPG)
#define NTOT (NG*NPG)
#define KKEEP 640
#define KDROP 160
#define MAXDEG 64

// output section offsets (in floats)
#define OFF_CX    0u
#define OFF_CEI   6400000u
#define OFF_CATTR 7040000u
#define OFF_CW    7360000u
#define OFF_CB    7680000u
#define OFF_FX    7730000u
#define OFF_FEI   14130000u
#define OFF_FATTR 14290000u
#define OFF_FW    14370000u
#define OFF_FB    14450000u
#define OFF_ES    14500000u

// ---------------------------------------------------------------------------
// prep: per-dst incoming edge lists as (ew, src) pairs + weighted degree.
// ---------------------------------------------------------------------------
__global__ __launch_bounds__(128) void prep_kernel(
    const int* __restrict__ ei, const float* __restrict__ ea,
    float2* __restrict__ elist2, int* __restrict__ ecnt, float* __restrict__ sdeg)
{
  __shared__ unsigned char esrcL[EPG];
  __shared__ unsigned char edstL[EPG];
  __shared__ float ewvL[EPG];
  const int g = blockIdx.x, t = threadIdx.x;
  const int nb = g * NPG;
  for (int e = t; e < EPG; e += 128) {
    int ge = g * EPG + e;
    esrcL[e] = (unsigned char)(ei[ge] - nb);
    edstL[e] = (unsigned char)(ei[ETOT + ge] - nb);
    ewvL[e] = ea[ge];
  }
  __syncthreads();
  if (t < NPG) {
    int cnt = 0; float s = 0.f;
    float2* lp = elist2 + (size_t)(nb + t) * MAXDEG;
    for (int e = 0; e < EPG; e++) {
      if ((int)edstL[e] == t) {
        if (cnt < MAXDEG) lp[cnt] = make_float2(ewvL[e], __int_as_float((int)esrcL[e]));
        cnt++; s += ewvL[e];
      }
    }
    ecnt[nb + t] = cnt < MAXDEG ? cnt : MAXDEG;
    sdeg[nb + t] = s;
  }
}

// ---------------------------------------------------------------------------
// preagg: y[d] = sum_e ew * x[src_e]
// ---------------------------------------------------------------------------
template<int K>
__global__ __launch_bounds__(512) void preagg_kernel(
    const float* __restrict__ xin, const float2* __restrict__ elist2,
    const int* __restrict__ ecnt, float* __restrict__ y)
{
  __shared__ float xt[NPG][K];
  const int g = blockIdx.x, t = threadIdx.x;
  const int nb = g * NPG;
  for (int i = t; i < NPG * K / 4; i += 512)
    ((float4*)xt)[i] = ((const float4*)(xin + (size_t)nb * K))[i];
  __syncthreads();
  const int c = t % K, grp = t / K;
  const int NGRP = 512 / K;
  for (int d = grp; d < NPG; d += NGRP) {
    const int cn = ecnt[nb + d];
    const float2* lp = elist2 + (size_t)(nb + d) * MAXDEG;
    float acc = 0.f;
    for (int j = 0; j < cn; j++) {
      float2 p = lp[j];
      acc += p.x * xt[__float_as_int(p.y)][c];
    }
    y[(size_t)(nb + d) * K + c] = acc;
  }
}

// ---------------------------------------------------------------------------
// conv GEMM: h = [y | x | sd*x] @ [w1; w3; -w2] + sd*b1 + b3  (opt relu)
// ---------------------------------------------------------------------------
template<int K, bool RELU>
__global__ __launch_bounds__(256) void conv_gemm_kernel(
    const float* __restrict__ y, const float* __restrict__ xin, const float* __restrict__ sdeg,
    const float* __restrict__ w1, const float* __restrict__ w2, const float* __restrict__ w3,
    const float* __restrict__ b1, const float* __restrict__ b3,
    float* __restrict__ hout)
{
  __shared__ float wl[64][HID];   // 32KB B' chunk
  const int t = threadIdx.x;
  const int m0 = blockIdx.x * 128;
  const int tc = t % 16;
  const int tr = t / 16;
  float acc[8][8];
#pragma unroll
  for (int i = 0; i < 8; i++)
#pragma unroll
    for (int j = 0; j < 8; j++) acc[i][j] = 0.f;

  int rowc[8]; float sdv[8];
#pragma unroll
  for (int i = 0; i < 8; i++) {
    int r = m0 + tr * 8 + i;
    rowc[i] = r < NTOT ? r : NTOT - 1;
    sdv[i] = sdeg[rowc[i]];
  }
  const int NCH = (3 * K) / 64;
  for (int ch = 0; ch < NCH; ++ch) {
    __syncthreads();
    for (int i = t; i < 64 * HID / 4; i += 256) {
      int kk = i / 32, q = i % 32;
      int kr = ch * 64 + kk;
      int seg = kr / K; int sr = kr % K;
      const float* wp = seg == 0 ? w1 : (seg == 1 ? w3 : w2);
      float4 v = *(const float4*)(wp + (size_t)sr * HID + q * 4);
      if (seg == 2) { v.x = -v.x; v.y = -v.y; v.z = -v.z; v.w = -v.w; }
      *(float4*)&wl[kk][q * 4] = v;
    }
    __syncthreads();
    const int seg = (ch * 64) / K;
    const int kb = (ch * 64) % K;
    for (int k4 = 0; k4 < 16; ++k4) {
      float4 a4[8];
#pragma unroll
      for (int i = 0; i < 8; i++) {
        const float* src = (seg == 0 ? y : xin) + (size_t)rowc[i] * K + kb + k4 * 4;
        float4 v = *(const float4*)src;
        if (seg == 2) { float s = sdv[i]; v.x *= s; v.y *= s; v.z *= s; v.w *= s; }
        a4[i] = v;
      }
#pragma unroll
      for (int kk = 0; kk < 4; kk++) {
        float wv0[4], wv1[4];
        *(float4*)wv0 = *(const float4*)&wl[k4 * 4 + kk][tc * 4];
        *(float4*)wv1 = *(const float4*)&wl[k4 * 4 + kk][64 + tc * 4];
#pragma unroll
        for (int i = 0; i < 8; i++) {
          const float av = (&a4[i].x)[kk];
#pragma unroll
          for (int j = 0; j < 4; j++) {
            acc[i][j]     += av * wv0[j];
            acc[i][4 + j] += av * wv1[j];
          }
        }
      }
    }
  }
#pragma unroll
  for (int i = 0; i < 8; i++) {
    const int r = m0 + tr * 8 + i;
    if (r < NTOT) {
      float4 o0, o1;
#pragma unroll
      for (int j = 0; j < 4; j++) {
        float c0 = acc[i][j]     + sdv[i] * b1[tc * 4 + j]      + b3[tc * 4 + j];
        float c1 = acc[i][4 + j] + sdv[i] * b1[64 + tc * 4 + j] + b3[64 + tc * 4 + j];
        if (RELU) { c0 = fmaxf(c0, 0.f); c1 = fmaxf(c1, 0.f); }
        (&o0.x)[j] = c0; (&o1.x)[j] = c1;
      }
      float* op = hout + (size_t)r * HID;
      *(float4*)(op + tc * 4) = o0;
      *(float4*)(op + 64 + tc * 4) = o1;
    }
  }
}

// ---------------------------------------------------------------------------
// pq_gemm: PQ[n][0:512] = h2@W1a + b1 (P), PQ[n][512:1024] = h2@W1b (Q)
// One 50000 x 1024 x 128 GEMM, 128x128 tiles, 8x8 register tiles.
// ---------------------------------------------------------------------------
__global__ __launch_bounds__(256) void pq_gemm_kernel(
    const float* __restrict__ h2, const float* __restrict__ mw1, const float* __restrict__ mb1,
    float* __restrict__ PQ)
{
  __shared__ float wl[64][HID];   // 32KB
  const int t = threadIdx.x;
  const int m0 = blockIdx.x * 128;
  const int n0 = blockIdx.y * 128;      // 0..1023, never straddles 512
  const int tc = t % 16, tr = t / 16;
  const int basek = (n0 >= 512) ? HID : 0;
  const int cbase = n0 & 511;

  float acc[8][8];
#pragma unroll
  for (int i = 0; i < 8; i++) {
#pragma unroll
    for (int j = 0; j < 4; j++) {
      acc[i][j]     = (basek == 0) ? mb1[n0 + tc * 4 + j] : 0.f;
      acc[i][4 + j] = (basek == 0) ? mb1[n0 + 64 + tc * 4 + j] : 0.f;
    }
  }
  int rowc[8];
#pragma unroll
  for (int i = 0; i < 8; i++) {
    int r = m0 + tr * 8 + i;
    rowc[i] = r < NTOT ? r : NTOT - 1;
  }

  for (int ch = 0; ch < 2; ++ch) {
    __syncthreads();
    for (int i = t; i < 64 * 32; i += 256) {
      int kk = i / 32, q = i % 32;
      *(float4*)&wl[kk][q * 4] =
          *(const float4*)(mw1 + (size_t)(basek + ch * 64 + kk) * 512 + cbase + q * 4);
    }
    __syncthreads();
    for (int k4 = 0; k4 < 16; ++k4) {
      float4 a4[8];
#pragma unroll
      for (int i = 0; i < 8; i++)
        a4[i] = *(const float4*)(h2 + (size_t)rowc[i] * HID + ch * 64 + k4 * 4);
#pragma unroll
      for (int kk = 0; kk < 4; kk++) {
        float wv0[4], wv1[4];
        *(float4*)wv0 = *(const float4*)&wl[k4 * 4 + kk][tc * 4];
        *(float4*)wv1 = *(const float4*)&wl[k4 * 4 + kk][64 + tc * 4];
#pragma unroll
        for (int i = 0; i < 8; i++) {
          const float av = (&a4[i].x)[kk];
#pragma unroll
          for (int j = 0; j < 4; j++) {
            acc[i][j]     += av * wv0[j];
            acc[i][4 + j] += av * wv1[j];
          }
        }
      }
    }
  }
#pragma unroll
  for (int i = 0; i < 8; i++) {
    const int r = m0 + tr * 8 + i;
    if (r < NTOT) {
      float* op = PQ + (size_t)r * 1024 + n0;
      *(float4*)(op + tc * 4)      = *(float4*)&acc[i][0];
      *(float4*)(op + 64 + tc * 4) = *(float4*)&acc[i][4];
    }
  }
}

// ---------------------------------------------------------------------------
// edge_sort: per-graph. Stage P/Q 64-col chunks into padded LDS, score 800
// edges (fp64 chunk accumulation), then bitonic sort + top-K split + presence
// + local relabel ranks — all in one block.
// ---------------------------------------------------------------------------
__global__ __launch_bounds__(256) void edge_sort_kernel(
    const float* __restrict__ PQ, const int* __restrict__ ei,
    const float* __restrict__ mw2, const float* __restrict__ mb2,
    float* __restrict__ scores_ws, float* __restrict__ out_es,
    int* __restrict__ keptEid, int* __restrict__ dropEid,
    int* __restrict__ cLocal, int* __restrict__ fLocal,
    int* __restrict__ cCount, int* __restrict__ fCount)
{
  __shared__ float Pl[NPG][68];   // +4 pad: random-row b128 reads spread banks
  __shared__ float Ql[NPG][68];
  __shared__ float w2l[64];
  __shared__ unsigned char esrcL[EPG];
  __shared__ unsigned char edstL[EPG];
  __shared__ unsigned long long keys[1024];
  __shared__ int cpres[NPG];
  __shared__ int fpres[NPG];

  const int g = blockIdx.x, t = threadIdx.x;
  const int nb = g * NPG;

  for (int e = t; e < EPG; e += 256) {
    int ge = g * EPG + e;
    esrcL[e] = (unsigned char)(ei[ge] - nb);
    edstL[e] = (unsigned char)(ei[ETOT + ge] - nb);
  }
  for (int i = t; i < NPG; i += 256) { cpres[i] = 0; fpres[i] = 0; }
  __syncthreads();

  int sl[4], dl[4];
#pragma unroll
  for (int m = 0; m < 4; m++) {
    const int e = t + 256 * m;
    const int ec = e < EPG ? e : 0;
    sl[m] = esrcL[ec]; dl[m] = edstL[ec];
  }
  double accd[4];
#pragma unroll
  for (int m = 0; m < 4; m++) accd[m] = 0.;

  for (int ch = 0; ch < 8; ++ch) {
    __syncthreads();   // previous edge phase done reading Pl/Ql
    for (int i = t; i < NPG * 16; i += 256) {
      const int r = i >> 4, q = i & 15;
      const float* src = PQ + (size_t)(nb + r) * 1024 + ch * 64 + q * 4;
      *(float4*)&Pl[r][q * 4] = *(const float4*)src;
      *(float4*)&Ql[r][q * 4] = *(const float4*)(src + 512);
    }
    if (t < 16) *(float4*)&w2l[t * 4] = *(const float4*)(mw2 + ch * 64 + t * 4);
    __syncthreads();
#pragma unroll
    for (int m = 0; m < 4; m++) {
      double aa = 0.;
      for (int j4 = 0; j4 < 16; ++j4) {
        const float4 p = *(const float4*)&Pl[sl[m]][j4 * 4];
        const float4 q = *(const float4*)&Ql[dl[m]][j4 * 4];
        const float4 w = *(const float4*)&w2l[j4 * 4];
        const float s = fmaxf(p.x + q.x, 0.f) * w.x + fmaxf(p.y + q.y, 0.f) * w.y
                      + fmaxf(p.z + q.z, 0.f) * w.z + fmaxf(p.w + q.w, 0.f) * w.w;
        aa += (double)s;
      }
      accd[m] += aa;
    }
  }

  // scores out + sort keys
  const double b2v = (double)mb2[0];
#pragma unroll
  for (int m = 0; m < 4; m++) {
    const int e = t + 256 * m;
    if (e < EPG) {
      const float sc = (float)(accd[m] + b2v);
      const int ge = g * EPG + e;
      scores_ws[ge] = sc; out_es[ge] = sc;
      const unsigned int bb = __float_as_uint(sc);
      const unsigned int mm = (bb & 0x80000000u) ? (~bb) : (bb | 0x80000000u);
      keys[e] = ((unsigned long long)(~mm) << 32) | (unsigned int)e;
    }
  }
  if (t >= 32) keys[t + 768] = 0xFFFFFFFFFFFFFFFFull;   // pads 800..1023
  __syncthreads();

  for (int k = 2; k <= 1024; k <<= 1) {
    for (int j = k >> 1; j > 0; j >>= 1) {
      for (int i = t; i < 1024; i += 256) {
        const int l = i ^ j;
        if (l > i) {
          const bool up = ((i & k) == 0);
          const unsigned long long va = keys[i], vb = keys[l];
          if ((va > vb) == up) { keys[i] = vb; keys[l] = va; }
        }
      }
      __syncthreads();
    }
  }

  for (int r = t; r < EPG; r += 256) {
    const int el = (int)(unsigned int)keys[r];
    const int ge = g * EPG + el;
    const int s0 = esrcL[el], d0 = edstL[el];
    if (r < KKEEP) {
      keptEid[g * KKEEP + r] = ge;
      cpres[s0] = 1; cpres[d0] = 1;
    } else {
      dropEid[g * KDROP + (r - KKEEP)] = ge;
      fpres[s0] = 1; fpres[d0] = 1;
    }
  }
  __syncthreads();

  if (t == 0) {
    int cc = 0;
    for (int v = 0; v < NPG; v++) { const int pr = cpres[v]; cLocal[nb + v] = pr ? cc : -1; cc += pr; }
    cCount[g] = cc;
  }
  if (t == 64) {
    int fc = 0;
    for (int v = 0; v < NPG; v++) { const int pr = fpres[v]; fLocal[nb + v] = pr ? fc : -1; fc += pr; }
    fCount[g] = fc;
  }
}

__global__ __launch_bounds__(512) void offsets_kernel(
    const int* __restrict__ cCount, const int* __restrict__ fCount,
    int* __restrict__ cOff, int* __restrict__ fOff)
{
  __shared__ int sc[512];
  __shared__ int sf[512];
  const int t = threadIdx.x;
  const int c0 = (t < NG) ? cCount[t] : 0;
  const int f0 = (t < NG) ? fCount[t] : 0;
  sc[t] = c0; sf[t] = f0;
  __syncthreads();
  for (int off = 1; off < 512; off <<= 1) {
    const int ac = (t >= off) ? sc[t - off] : 0;
    const int af = (t >= off) ? sf[t - off] : 0;
    __syncthreads();
    sc[t] += ac; sf[t] += af;
    __syncthreads();
  }
  if (t < NG) { cOff[t] = sc[t] - c0; fOff[t] = sf[t] - f0; }
  if (t == NG - 1) { cOff[NG] = sc[t]; fOff[NG] = sf[t]; }
}

__global__ __launch_bounds__(256) void scatter_kernel(
    const float* __restrict__ h2, const int* __restrict__ cLocal, const int* __restrict__ fLocal,
    const int* __restrict__ cOff, const int* __restrict__ fOff,
    int* __restrict__ nodeIdxC, int* __restrict__ nodeIdxF, float* __restrict__ out)
{
  const int tid = blockIdx.x * 256 + threadIdx.x;
  if (tid >= 2 * NTOT * 32) return;
  const int side = tid >= NTOT * 32 ? 1 : 0;
  const int rem = tid - side * NTOT * 32;
  const int v = rem >> 5, q = rem & 31;
  const int loc = side ? fLocal[v] : cLocal[v];
  if (loc < 0) return;
  const int g = v / NPG;
  const int pos = (side ? fOff[g] : cOff[g]) + loc;
  const float4* srcv = (const float4*)(h2 + (size_t)v * HID);
  float4* dstv = (float4*)(out + (side ? OFF_FX : OFF_CX) + (size_t)pos * HID);
  dstv[q] = srcv[q];
  if (q == 0) {
    (side ? nodeIdxF : nodeIdxC)[v] = pos;
    out[(side ? OFF_FB : OFF_CB) + pos] = (float)g;
  }
}

__global__ __launch_bounds__(256) void fill_kernel(
    const int* __restrict__ cOff, const int* __restrict__ fOff, float* __restrict__ out)
{
  const int tid = blockIdx.x * 256 + threadIdx.x;
  if (tid >= 2 * NTOT * 32) return;
  const int side = tid >= NTOT * 32 ? 1 : 0;
  const int rem = tid - side * NTOT * 32;
  const int r = rem >> 5, q = rem & 31;
  const int total = side ? fOff[NG] : cOff[NG];
  if (r < total) return;
  float4 z; z.x = 0.f; z.y = 0.f; z.z = 0.f; z.w = 0.f;
  ((float4*)(out + (side ? OFF_FX : OFF_CX)))[(size_t)r * 32 + q] = z;
  if (q == 0) out[(side ? OFF_FB : OFF_CB) + r] = -1.0f;
}

__global__ __launch_bounds__(256) void edgeout_kernel(
    const int* __restrict__ ei, const float* __restrict__ ea, const float* __restrict__ scores,
    const int* __restrict__ keptEid, const int* __restrict__ dropEid,
    const int* __restrict__ nodeIdxC, const int* __restrict__ nodeIdxF, float* __restrict__ out)
{
  const int tid = blockIdx.x * 256 + threadIdx.x;
  if (tid >= ETOT) return;
  if (tid < NG * KKEEP) {
    const int ge = keptEid[tid];
    out[OFF_CEI + tid] = (float)nodeIdxC[ei[ge]];
    out[OFF_CEI + 320000 + tid] = (float)nodeIdxC[ei[ETOT + ge]];
    out[OFF_CATTR + tid] = ea[ge];
    out[OFF_CW + tid] = scores[ge];
  } else {
    const int i = tid - NG * KKEEP;
    const int ge = dropEid[i];
    out[OFF_FEI + i] = (float)nodeIdxF[ei[ge]];
    out[OFF_FEI + 80000 + i] = (float)nodeIdxF[ei[ETOT + ge]];
    out[OFF_FATTR + i] = ea[ge];
    out[OFF_FW + i] = -scores[ge];
  }
}

extern "C" void kernel_launch(void* const* d_in, const int* in_sizes, int n_in,
                              void* d_out, int out_size, void* d_ws, size_t ws_size,
                              hipStream_t stream) {
  const float* x    = (const float*)d_in[0];
  const int*   ei   = (const int*)d_in[1];
  const float* ea   = (const float*)d_in[2];
  const float* c1w1 = (const float*)d_in[4];
  const float* c1b1 = (const float*)d_in[5];
  const float* c1w2 = (const float*)d_in[6];
  const float* c1w3 = (const float*)d_in[7];
  const float* c1b3 = (const float*)d_in[8];
  const float* c2w1 = (const float*)d_in[9];
  const float* c2b1 = (const float*)d_in[10];
  const float* c2w2 = (const float*)d_in[11];
  const float* c2w3 = (const float*)d_in[12];
  const float* c2b3 = (const float*)d_in[13];
  const float* mw1  = (const float*)d_in[14];
  const float* mb1  = (const float*)d_in[15];
  const float* mw2  = (const float*)d_in[16];
  const float* mb2  = (const float*)d_in[17];
  float* out = (float*)d_out;

  char* p = (char*)d_ws;
  auto carve = [&](size_t bytes) { void* r = (void*)p; p += (bytes + 255) & ~(size_t)255; return r; };
  // persistent-through-pipeline allocations first
  float* h2      = (float*)carve((size_t)NTOT * HID * 4);
  float* scores  = (float*)carve((size_t)ETOT * 4);
  int* keptEid   = (int*)carve((size_t)NG * KKEEP * 4);
  int* dropEid   = (int*)carve((size_t)NG * KDROP * 4);
  int* cLocal    = (int*)carve((size_t)NTOT * 4);
  int* fLocal    = (int*)carve((size_t)NTOT * 4);
  int* cCount    = (int*)carve((size_t)NG * 4);
  int* fCount    = (int*)carve((size_t)NG * 4);
  int* cOff      = (int*)carve((size_t)(NG + 1) * 4);
  int* fOff      = (int*)carve((size_t)(NG + 1) * 4);
  int* nodeIdxC  = (int*)carve((size_t)NTOT * 4);
  int* nodeIdxF  = (int*)carve((size_t)NTOT * 4);
  // union region: {h1, ybuf, elist2, ecnt, sdeg} (conv phase)  OVERLAID BY
  // PQ [NTOT][1024] (score phase) — h1/ybuf/elist2/ecnt/sdeg are dead once
  // conv2 has written h2.
  char* ub = (char*)carve((size_t)NTOT * 1024 * 4);
  float* PQ      = (float*)ub;
  float* h1      = (float*)ub;
  float* ybuf    = (float*)(ub + (size_t)NTOT * HID * 4);
  float2* elist2 = (float2*)(ub + (size_t)2 * NTOT * HID * 4);
  int* ecnt      = (int*)(ub + (size_t)2 * NTOT * HID * 4 + (size_t)NTOT * MAXDEG * 8);
  float* sdeg    = (float*)(ub + (size_t)2 * NTOT * HID * 4 + (size_t)NTOT * MAXDEG * 8 + (size_t)NTOT * 4);

  const int MT = (NTOT + 127) / 128;

  prep_kernel<<<NG, 128, 0, stream>>>(ei, ea, elist2, ecnt, sdeg);
  preagg_kernel<INDIM><<<NG, 512, 0, stream>>>(x, elist2, ecnt, ybuf);
  conv_gemm_kernel<INDIM, true><<<MT, 256, 0, stream>>>(ybuf, x, sdeg, c1w1, c1w2, c1w3, c1b1, c1b3, h1);
  preagg_kernel<HID><<<NG, 512, 0, stream>>>(h1, elist2, ecnt, ybuf);
  conv_gemm_kernel<HID, false><<<MT, 256, 0, stream>>>(ybuf, h1, sdeg, c2w1, c2w2, c2w3, c2b1, c2b3, h2);
  dim3 pqgrid(MT, 8);
  pq_gemm_kernel<<<pqgrid, 256, 0, stream>>>(h2, mw1, mb1, PQ);
  edge_sort_kernel<<<NG, 256, 0, stream>>>(PQ, ei, mw2, mb2, scores, out + OFF_ES,
                                           keptEid, dropEid, cLocal, fLocal, cCount, fCount);
  offsets_kernel<<<1, 512, 0, stream>>>(cCount, fCount, cOff, fOff);
  const int sc_threads = 2 * NTOT * 32;
  scatter_kernel<<<(sc_threads + 255) / 256, 256, 0, stream>>>(h2, cLocal, fLocal, cOff, fOff, nodeIdxC, nodeIdxF, out);
  fill_kernel<<<(sc_threads + 255) / 256, 256, 0, stream>>>(cOff, fOff, out);
  edgeout_kernel<<<(ETOT + 255) / 256, 256, 0, stream>>>(ei, ea, scores, keptEid, dropEid, nodeIdxC, nodeIdxF, out);
}

// Round 7
// 778.869 us; speedup vs baseline: 1.4978x; 1.0696x over previous
//
#include <hip/hip_runtime.h>

#define NG 500
#define NPG 100
#define EPG 800
#define INDIM 64
#define HID 128
#define ETOT (NG*EPG)
#define NTOT (NG*NPG)
#define KKEEP 640
#define KDROP 160
#define MAXDEG 64

// output section offsets (in floats)
#define OFF_CX    0u
#define OFF_CEI   6400000u
#define OFF_CATTR 7040000u
#define OFF_CW    7360000u
#define OFF_CB    7680000u
#define OFF_FX    7730000u
#define OFF_FEI   14130000u
#define OFF_FATTR 14290000u
#define OFF_FW    14370000u
#define OFF_FB    14450000u
#define OFF_ES    14500000u

// ---------------------------------------------------------------------------
// prep: per-dst incoming edge lists as (ew, src) pairs + weighted degree.
// ---------------------------------------------------------------------------
__global__ __launch_bounds__(128) void prep_kernel(
    const int* __restrict__ ei, const float* __restrict__ ea,
    float2* __restrict__ elist2, int* __restrict__ ecnt, float* __restrict__ sdeg)
{
  __shared__ unsigned char esrcL[EPG];
  __shared__ unsigned char edstL[EPG];
  __shared__ float ewvL[EPG];
  const int g = blockIdx.x, t = threadIdx.x;
  const int nb = g * NPG;
  for (int e = t; e < EPG; e += 128) {
    int ge = g * EPG + e;
    esrcL[e] = (unsigned char)(ei[ge] - nb);
    edstL[e] = (unsigned char)(ei[ETOT + ge] - nb);
    ewvL[e] = ea[ge];
  }
  __syncthreads();
  if (t < NPG) {
    int cnt = 0; float s = 0.f;
    float2* lp = elist2 + (size_t)(nb + t) * MAXDEG;
    for (int e = 0; e < EPG; e++) {
      if ((int)edstL[e] == t) {
        if (cnt < MAXDEG) lp[cnt] = make_float2(ewvL[e], __int_as_float((int)esrcL[e]));
        cnt++; s += ewvL[e];
      }
    }
    ecnt[nb + t] = cnt < MAXDEG ? cnt : MAXDEG;
    sdeg[nb + t] = s;
  }
}

// ---------------------------------------------------------------------------
// preagg: y[d] = sum_e ew * x[src_e]
// ---------------------------------------------------------------------------
template<int K>
__global__ __launch_bounds__(512) void preagg_kernel(
    const float* __restrict__ xin, const float2* __restrict__ elist2,
    const int* __restrict__ ecnt, float* __restrict__ y)
{
  __shared__ float xt[NPG][K];
  const int g = blockIdx.x, t = threadIdx.x;
  const int nb = g * NPG;
  for (int i = t; i < NPG * K / 4; i += 512)
    ((float4*)xt)[i] = ((const float4*)(xin + (size_t)nb * K))[i];
  __syncthreads();
  const int c = t % K, grp = t / K;
  const int NGRP = 512 / K;
  for (int d = grp; d < NPG; d += NGRP) {
    const int cn = ecnt[nb + d];
    const float2* lp = elist2 + (size_t)(nb + d) * MAXDEG;
    float acc = 0.f;
    for (int j = 0; j < cn; j++) {
      float2 p = lp[j];
      acc += p.x * xt[__float_as_int(p.y)][c];
    }
    y[(size_t)(nb + d) * K + c] = acc;
  }
}

// ---------------------------------------------------------------------------
// conv GEMM: h = [y | x | sd*x] @ [w1; w3; -w2] + sd*b1 + b3  (opt relu)
// A-chunk staged in padded LDS (al) to kill 16x redundant global A reads.
// ---------------------------------------------------------------------------
template<int K, bool RELU>
__global__ __launch_bounds__(256) void conv_gemm_kernel(
    const float* __restrict__ y, const float* __restrict__ xin, const float* __restrict__ sdeg,
    const float* __restrict__ w1, const float* __restrict__ w2, const float* __restrict__ w3,
    const float* __restrict__ b1, const float* __restrict__ b3,
    float* __restrict__ hout)
{
  __shared__ float wl[64][HID];   // 32KB B' chunk
  __shared__ float al[128][68];   // 34.8KB A chunk (padded: (68r)%32=4r spreads)
  const int t = threadIdx.x;
  const int m0 = blockIdx.x * 128;
  const int tc = t % 16;
  const int tr = t / 16;
  float acc[8][8];
#pragma unroll
  for (int i = 0; i < 8; i++)
#pragma unroll
    for (int j = 0; j < 8; j++) acc[i][j] = 0.f;

  int rowc[8]; float sdv[8];
#pragma unroll
  for (int i = 0; i < 8; i++) {
    int r = m0 + tr * 8 + i;
    rowc[i] = r < NTOT ? r : NTOT - 1;
    sdv[i] = sdeg[rowc[i]];
  }
  const int NCH = (3 * K) / 64;
  for (int ch = 0; ch < NCH; ++ch) {
    __syncthreads();
    const int seg = (ch * 64) / K;
    const int kb = (ch * 64) % K;
    // stage B' chunk
    for (int i = t; i < 64 * HID / 4; i += 256) {
      int kk = i / 32, q = i % 32;
      int kr = ch * 64 + kk;
      int sr = kr % K;
      const float* wp = seg == 0 ? w1 : (seg == 1 ? w3 : w2);
      float4 v = *(const float4*)(wp + (size_t)sr * HID + q * 4);
      if (seg == 2) { v.x = -v.x; v.y = -v.y; v.z = -v.z; v.w = -v.w; }
      *(float4*)&wl[kk][q * 4] = v;
    }
    // stage A chunk (rows m0..m0+127, k kb..kb+63), sd-scaled for seg 2
    {
      const float* abase = (seg == 0 ? y : xin);
      for (int i = t; i < 128 * 16; i += 256) {
        int r = i / 16, q = i % 16;
        int gr = m0 + r; if (gr >= NTOT) gr = NTOT - 1;
        float4 v = *(const float4*)(abase + (size_t)gr * K + kb + q * 4);
        if (seg == 2) { float s = sdeg[gr]; v.x *= s; v.y *= s; v.z *= s; v.w *= s; }
        *(float4*)&al[r][q * 4] = v;
      }
    }
    __syncthreads();
    for (int k4 = 0; k4 < 16; ++k4) {
      float4 a4[8];
#pragma unroll
      for (int i = 0; i < 8; i++)
        a4[i] = *(const float4*)&al[tr * 8 + i][k4 * 4];
#pragma unroll
      for (int kk = 0; kk < 4; kk++) {
        float wv0[4], wv1[4];
        *(float4*)wv0 = *(const float4*)&wl[k4 * 4 + kk][tc * 4];
        *(float4*)wv1 = *(const float4*)&wl[k4 * 4 + kk][64 + tc * 4];
#pragma unroll
        for (int i = 0; i < 8; i++) {
          const float av = (&a4[i].x)[kk];
#pragma unroll
          for (int j = 0; j < 4; j++) {
            acc[i][j]     += av * wv0[j];
            acc[i][4 + j] += av * wv1[j];
          }
        }
      }
    }
  }
#pragma unroll
  for (int i = 0; i < 8; i++) {
    const int r = m0 + tr * 8 + i;
    if (r < NTOT) {
      float4 o0, o1;
#pragma unroll
      for (int j = 0; j < 4; j++) {
        float c0 = acc[i][j]     + sdv[i] * b1[tc * 4 + j]      + b3[tc * 4 + j];
        float c1 = acc[i][4 + j] + sdv[i] * b1[64 + tc * 4 + j] + b3[64 + tc * 4 + j];
        if (RELU) { c0 = fmaxf(c0, 0.f); c1 = fmaxf(c1, 0.f); }
        (&o0.x)[j] = c0; (&o1.x)[j] = c1;
      }
      float* op = hout + (size_t)r * HID;
      *(float4*)(op + tc * 4) = o0;
      *(float4*)(op + 64 + tc * 4) = o1;
    }
  }
}

// ---------------------------------------------------------------------------
// score_sort: fused per-graph. h2 tile staged once in LDS; per 32-col chunk:
// stage W1 chunk in LDS, GEMM (4 rows x 2 cols/thread) -> Pl/Ql, edge phase
// (fp64 per-4-term accumulation, k-ascending — bit-matches the unfused
// version). Then bitonic sort + top-K split + presence + relabel in-block.
// 1024 threads, ~125 KB LDS, 1 block/CU, 16 waves.
// ---------------------------------------------------------------------------
__global__ __launch_bounds__(1024) void score_sort_kernel(
    const float* __restrict__ h2, const int* __restrict__ ei,
    const float* __restrict__ mw1, const float* __restrict__ mb1,
    const float* __restrict__ mw2, const float* __restrict__ mb2,
    float* __restrict__ scores_ws, float* __restrict__ out_es,
    int* __restrict__ keptEid, int* __restrict__ dropEid,
    int* __restrict__ cLocal, int* __restrict__ fLocal,
    int* __restrict__ cCount, int* __restrict__ fCount)
{
  __shared__ float h2t[NPG][HID];      // 51.2 KB
  __shared__ float wl[HID][66];        // 33.8 KB: [k][0:32]=P cols, [32:64]=Q cols
  __shared__ float Pl[NPG][34];        // 13.6 KB (stride 34: edge reads 4-way max)
  __shared__ float Ql[NPG][34];        // 13.6 KB
  __shared__ float w2l[512];           // 2 KB
  __shared__ unsigned char esrcL[EPG];
  __shared__ unsigned char edstL[EPG];
  __shared__ unsigned long long keys[1024]; // 8 KB
  __shared__ int cpres[NPG];
  __shared__ int fpres[NPG];

  const int g = blockIdx.x, t = threadIdx.x;
  const int nb = g * NPG;

  for (int i = t; i < NPG * HID / 4; i += 1024)
    ((float4*)h2t)[i] = ((const float4*)(h2 + (size_t)nb * HID))[i];
  if (t < EPG) {
    int ge = g * EPG + t;
    esrcL[t] = (unsigned char)(ei[ge] - nb);
    edstL[t] = (unsigned char)(ei[ETOT + ge] - nb);
  }
  if (t < 128) *(float4*)&w2l[t * 4] = *(const float4*)(mw2 + t * 4);
  if (t < NPG) { cpres[t] = 0; fpres[t] = 0; }
  __syncthreads();

  const int tc = t & 31, tr = t >> 5;          // tr<25: rows tr*4..+3
  const int isQ = tc >> 4;
  const int cj = (tc & 15) * 2;                // col pair within 32-half
  const int wcol = isQ * 32 + cj;
  int sl = 0, dl = 0;
  if (t < EPG) { sl = esrcL[t]; dl = edstL[t]; }
  double accd = 0.;

  for (int ch = 0; ch < 16; ++ch) {
    // stage W chunk: P = mw1[k][ch*32+q], Q = mw1[128+k][ch*32+q]
    for (int i = t; i < HID * 16; i += 1024) {
      const int k = i >> 4, q = i & 15;
      const float* src = (q < 8)
        ? (mw1 + (size_t)k * 512 + ch * 32 + q * 4)
        : (mw1 + (size_t)(HID + k) * 512 + ch * 32 + (q - 8) * 4);
      *(float4*)&wl[k][q * 4] = *(const float4*)src;
    }
    __syncthreads();
    if (tr < 25) {
      float acc0[4], acc1[4];
      const float b0 = isQ ? 0.f : mb1[ch * 32 + cj];
      const float b1v = isQ ? 0.f : mb1[ch * 32 + cj + 1];
#pragma unroll
      for (int i = 0; i < 4; i++) { acc0[i] = b0; acc1[i] = b1v; }
      for (int k4 = 0; k4 < 32; ++k4) {
        float4 a4[4];
#pragma unroll
        for (int i = 0; i < 4; i++)
          a4[i] = *(const float4*)&h2t[tr * 4 + i][k4 * 4];
#pragma unroll
        for (int kk = 0; kk < 4; kk++) {
          const float2 wv = *(const float2*)&wl[k4 * 4 + kk][wcol];
#pragma unroll
          for (int i = 0; i < 4; i++) {
            const float av = (&a4[i].x)[kk];
            acc0[i] += av * wv.x; acc1[i] += av * wv.y;
          }
        }
      }
#pragma unroll
      for (int i = 0; i < 4; i++) {
        float* dst = isQ ? &Ql[tr * 4 + i][cj] : &Pl[tr * 4 + i][cj];
        *(float2*)dst = make_float2(acc0[i], acc1[i]);
      }
    }
    __syncthreads();
    if (t < EPG) {
#pragma unroll 2
      for (int jg = 0; jg < 8; ++jg) {   // 4 score terms per group (fp64 add)
        const float2 pa = *(const float2*)&Pl[sl][jg * 4];
        const float2 pb = *(const float2*)&Pl[sl][jg * 4 + 2];
        const float2 qa = *(const float2*)&Ql[dl][jg * 4];
        const float2 qb = *(const float2*)&Ql[dl][jg * 4 + 2];
        const float* w = &w2l[ch * 32 + jg * 4];
        const float s = fmaxf(pa.x + qa.x, 0.f) * w[0] + fmaxf(pa.y + qa.y, 0.f) * w[1]
                      + fmaxf(pb.x + qb.x, 0.f) * w[2] + fmaxf(pb.y + qb.y, 0.f) * w[3];
        accd += (double)s;
      }
    }
    __syncthreads();   // edge phase done before wl/Pl/Ql overwrite
  }

  // scores out + sort keys
  if (t < EPG) {
    const float sc = (float)(accd + (double)mb2[0]);
    const int ge = g * EPG + t;
    scores_ws[ge] = sc; out_es[ge] = sc;
    const unsigned int bb = __float_as_uint(sc);
    const unsigned int mm = (bb & 0x80000000u) ? (~bb) : (bb | 0x80000000u);
    keys[t] = ((unsigned long long)(~mm) << 32) | (unsigned int)t;
  } else {
    keys[t] = 0xFFFFFFFFFFFFFFFFull;
  }
  __syncthreads();

  for (int k = 2; k <= 1024; k <<= 1) {
    for (int j = k >> 1; j > 0; j >>= 1) {
      const int l = t ^ j;
      if (l > t) {
        const bool up = ((t & k) == 0);
        const unsigned long long va = keys[t], vb = keys[l];
        if ((va > vb) == up) { keys[t] = vb; keys[l] = va; }
      }
      __syncthreads();
    }
  }

  if (t < EPG) {
    const int el = (int)(unsigned int)keys[t];
    const int ge = g * EPG + el;
    const int s0 = esrcL[el], d0 = edstL[el];
    if (t < KKEEP) {
      keptEid[g * KKEEP + t] = ge;
      cpres[s0] = 1; cpres[d0] = 1;
    } else {
      dropEid[g * KDROP + (t - KKEEP)] = ge;
      fpres[s0] = 1; fpres[d0] = 1;
    }
  }
  __syncthreads();

  if (t == 0) {
    int cc = 0;
    for (int v = 0; v < NPG; v++) { const int pr = cpres[v]; cLocal[nb + v] = pr ? cc : -1; cc += pr; }
    cCount[g] = cc;
  }
  if (t == 64) {
    int fc = 0;
    for (int v = 0; v < NPG; v++) { const int pr = fpres[v]; fLocal[nb + v] = pr ? fc : -1; fc += pr; }
    fCount[g] = fc;
  }
}

__global__ __launch_bounds__(512) void offsets_kernel(
    const int* __restrict__ cCount, const int* __restrict__ fCount,
    int* __restrict__ cOff, int* __restrict__ fOff)
{
  __shared__ int sc[512];
  __shared__ int sf[512];
  const int t = threadIdx.x;
  const int c0 = (t < NG) ? cCount[t] : 0;
  const int f0 = (t < NG) ? fCount[t] : 0;
  sc[t] = c0; sf[t] = f0;
  __syncthreads();
  for (int off = 1; off < 512; off <<= 1) {
    const int ac = (t >= off) ? sc[t - off] : 0;
    const int af = (t >= off) ? sf[t - off] : 0;
    __syncthreads();
    sc[t] += ac; sf[t] += af;
    __syncthreads();
  }
  if (t < NG) { cOff[t] = sc[t] - c0; fOff[t] = sf[t] - f0; }
  if (t == NG - 1) { cOff[NG] = sc[t]; fOff[NG] = sf[t]; }
}

__global__ __launch_bounds__(256) void scatter_kernel(
    const float* __restrict__ h2, const int* __restrict__ cLocal, const int* __restrict__ fLocal,
    const int* __restrict__ cOff, const int* __restrict__ fOff,
    int* __restrict__ nodeIdxC, int* __restrict__ nodeIdxF, float* __restrict__ out)
{
  const int tid = blockIdx.x * 256 + threadIdx.x;
  if (tid >= 2 * NTOT * 32) return;
  const int side = tid >= NTOT * 32 ? 1 : 0;
  const int rem = tid - side * NTOT * 32;
  const int v = rem >> 5, q = rem & 31;
  const int loc = side ? fLocal[v] : cLocal[v];
  if (loc < 0) return;
  const int g = v / NPG;
  const int pos = (side ? fOff[g] : cOff[g]) + loc;
  const float4* srcv = (const float4*)(h2 + (size_t)v * HID);
  float4* dstv = (float4*)(out + (side ? OFF_FX : OFF_CX) + (size_t)pos * HID);
  dstv[q] = srcv[q];
  if (q == 0) {
    (side ? nodeIdxF : nodeIdxC)[v] = pos;
    out[(side ? OFF_FB : OFF_CB) + pos] = (float)g;
  }
}

__global__ __launch_bounds__(256) void fill_kernel(
    const int* __restrict__ cOff, const int* __restrict__ fOff, float* __restrict__ out)
{
  const int tid = blockIdx.x * 256 + threadIdx.x;
  if (tid >= 2 * NTOT * 32) return;
  const int side = tid >= NTOT * 32 ? 1 : 0;
  const int rem = tid - side * NTOT * 32;
  const int r = rem >> 5, q = rem & 31;
  const int total = side ? fOff[NG] : cOff[NG];
  if (r < total) return;
  float4 z; z.x = 0.f; z.y = 0.f; z.z = 0.f; z.w = 0.f;
  ((float4*)(out + (side ? OFF_FX : OFF_CX)))[(size_t)r * 32 + q] = z;
  if (q == 0) out[(side ? OFF_FB : OFF_CB) + r] = -1.0f;
}

__global__ __launch_bounds__(256) void edgeout_kernel(
    const int* __restrict__ ei, const float* __restrict__ ea, const float* __restrict__ scores,
    const int* __restrict__ keptEid, const int* __restrict__ dropEid,
    const int* __restrict__ nodeIdxC, const int* __restrict__ nodeIdxF, float* __restrict__ out)
{
  const int tid = blockIdx.x * 256 + threadIdx.x;
  if (tid >= ETOT) return;
  if (tid < NG * KKEEP) {
    const int ge = keptEid[tid];
    out[OFF_CEI + tid] = (float)nodeIdxC[ei[ge]];
    out[OFF_CEI + 320000 + tid] = (float)nodeIdxC[ei[ETOT + ge]];
    out[OFF_CATTR + tid] = ea[ge];
    out[OFF_CW + tid] = scores[ge];
  } else {
    const int i = tid - NG * KKEEP;
    const int ge = dropEid[i];
    out[OFF_FEI + i] = (float)nodeIdxF[ei[ge]];
    out[OFF_FEI + 80000 + i] = (float)nodeIdxF[ei[ETOT + ge]];
    out[OFF_FATTR + i] = ea[ge];
    out[OFF_FW + i] = -scores[ge];
  }
}

extern "C" void kernel_launch(void* const* d_in, const int* in_sizes, int n_in,
                              void* d_out, int out_size, void* d_ws, size_t ws_size,
                              hipStream_t stream) {
  const float* x    = (const float*)d_in[0];
  const int*   ei   = (const int*)d_in[1];
  const float* ea   = (const float*)d_in[2];
  const float* c1w1 = (const float*)d_in[4];
  const float* c1b1 = (const float*)d_in[5];
  const float* c1w2 = (const float*)d_in[6];
  const float* c1w3 = (const float*)d_in[7];
  const float* c1b3 = (const float*)d_in[8];
  const float* c2w1 = (const float*)d_in[9];
  const float* c2b1 = (const float*)d_in[10];
  const float* c2w2 = (const float*)d_in[11];
  const float* c2w3 = (const float*)d_in[12];
  const float* c2b3 = (const float*)d_in[13];
  const float* mw1  = (const float*)d_in[14];
  const float* mb1  = (const float*)d_in[15];
  const float* mw2  = (const float*)d_in[16];
  const float* mb2  = (const float*)d_in[17];
  float* out = (float*)d_out;

  char* p = (char*)d_ws;
  auto carve = [&](size_t bytes) { void* r = (void*)p; p += (bytes + 255) & ~(size_t)255; return r; };
  float* h1      = (float*)carve((size_t)NTOT * HID * 4);
  float* h2      = (float*)carve((size_t)NTOT * HID * 4);
  float* ybuf    = (float*)carve((size_t)NTOT * HID * 4);
  float* scores  = (float*)carve((size_t)ETOT * 4);
  int* keptEid   = (int*)carve((size_t)NG * KKEEP * 4);
  int* dropEid   = (int*)carve((size_t)NG * KDROP * 4);
  int* cLocal    = (int*)carve((size_t)NTOT * 4);
  int* fLocal    = (int*)carve((size_t)NTOT * 4);
  int* cCount    = (int*)carve((size_t)NG * 4);
  int* fCount    = (int*)carve((size_t)NG * 4);
  int* cOff      = (int*)carve((size_t)(NG + 1) * 4);
  int* fOff      = (int*)carve((size_t)(NG + 1) * 4);
  int* nodeIdxC  = (int*)carve((size_t)NTOT * 4);
  int* nodeIdxF  = (int*)carve((size_t)NTOT * 4);
  float2* elist2 = (float2*)carve((size_t)NTOT * MAXDEG * 8);
  int* ecnt      = (int*)carve((size_t)NTOT * 4);
  float* sdeg    = (float*)carve((size_t)NTOT * 4);

  const int MT = (NTOT + 127) / 128;

  prep_kernel<<<NG, 128, 0, stream>>>(ei, ea, elist2, ecnt, sdeg);
  preagg_kernel<INDIM><<<NG, 512, 0, stream>>>(x, elist2, ecnt, ybuf);
  conv_gemm_kernel<INDIM, true><<<MT, 256, 0, stream>>>(ybuf, x, sdeg, c1w1, c1w2, c1w3, c1b1, c1b3, h1);
  preagg_kernel<HID><<<NG, 512, 0, stream>>>(h1, elist2, ecnt, ybuf);
  conv_gemm_kernel<HID, false><<<MT, 256, 0, stream>>>(ybuf, h1, sdeg, c2w1, c2w2, c2w3, c2b1, c2b3, h2);
  score_sort_kernel<<<NG, 1024, 0, stream>>>(h2, ei, mw1, mb1, mw2, mb2, scores, out + OFF_ES,
                                             keptEid, dropEid, cLocal, fLocal, cCount, fCount);
  offsets_kernel<<<1, 512, 0, stream>>>(cCount, fCount, cOff, fOff);
  const int sc_threads = 2 * NTOT * 32;
  scatter_kernel<<<(sc_threads + 255) / 256, 256, 0, stream>>>(h2, cLocal, fLocal, cOff, fOff, nodeIdxC, nodeIdxF, out);
  fill_kernel<<<(sc_threads + 255) / 256, 256, 0, stream>>>(cOff, fOff, out);
  edgeout_kernel<<<(ETOT + 255) / 256, 256, 0, stream>>>(ei, ea, scores, keptEid, dropEid, nodeIdxC, nodeIdxF, out);
}